// Round 12
// baseline (743.974 us; speedup 1.0000x reference)
//
#include <hip/hip_runtime.h>

typedef unsigned short u16;
typedef float f32x4 __attribute__((ext_vector_type(4)));
typedef __bf16 bf16x8 __attribute__((ext_vector_type(8)));
typedef u16 u16x8 __attribute__((ext_vector_type(8)));
typedef u16 u16x4 __attribute__((ext_vector_type(4)));

static constexpr int D  = 1024;
static constexpr int T  = 2048;
static constexpr int NB = 8;            // batch
static constexpr int M  = NB * T;       // 16384 rows
static constexpr int FF = 4096;
static constexpr int NCH = 32;          // scan chunks per sequence
static constexpr int CL  = T / NCH;     // 64 steps per chunk

__device__ __forceinline__ u16 f2bf(float f) {
  unsigned u = __builtin_bit_cast(unsigned, f);
  return (u16)((u + 0x7fffu + ((u >> 16) & 1u)) >> 16);   // RNE
}
__device__ __forceinline__ float bf2f(u16 s) {
  return __builtin_bit_cast(float, (unsigned)s << 16);
}

// async global->LDS 16B: LDS dest is wave-uniform base + lane*16 (m104);
// swizzling is done by pre-swizzling the per-lane GLOBAL address (m173).
__device__ __forceinline__ void gload16(const u16* g, u16* l) {
  __builtin_amdgcn_global_load_lds(
      (const __attribute__((address_space(1))) void*)g,
      (__attribute__((address_space(3))) void*)l, 16, 0, 0);
}

// ---------- fused LayerNorm + token-shift mix, 3 outputs (time-mix) ----------
__global__ __launch_bounds__(256) void lnmix3_kernel(const float* __restrict__ x,
    const float* __restrict__ g, const float* __restrict__ b,
    const float* __restrict__ mk, const float* __restrict__ mv, const float* __restrict__ mr,
    u16* __restrict__ xk, u16* __restrict__ xv, u16* __restrict__ xr) {
  __shared__ float red[16];
  const int m = blockIdx.x, tid = threadIdx.x;
  const bool first = (m % T) == 0;
  f32x4 v = *(const f32x4*)&x[(size_t)m * D + tid * 4];
  f32x4 vp = {0.0f, 0.0f, 0.0f, 0.0f};
  if (!first) vp = *(const f32x4*)&x[(size_t)(m - 1) * D + tid * 4];
  float s  = v[0] + v[1] + v[2] + v[3];
  float s2 = v[0]*v[0] + v[1]*v[1] + v[2]*v[2] + v[3]*v[3];
  float p  = vp[0] + vp[1] + vp[2] + vp[3];
  float p2 = vp[0]*vp[0] + vp[1]*vp[1] + vp[2]*vp[2] + vp[3]*vp[3];
  #pragma unroll
  for (int o = 32; o > 0; o >>= 1) {
    s += __shfl_down(s, o); s2 += __shfl_down(s2, o);
    p += __shfl_down(p, o); p2 += __shfl_down(p2, o);
  }
  if ((tid & 63) == 0) {
    red[tid >> 6] = s; red[4 + (tid >> 6)] = s2;
    red[8 + (tid >> 6)] = p; red[12 + (tid >> 6)] = p2;
  }
  __syncthreads();
  s  = red[0] + red[1] + red[2] + red[3];
  s2 = red[4] + red[5] + red[6] + red[7];
  p  = red[8] + red[9] + red[10] + red[11];
  p2 = red[12] + red[13] + red[14] + red[15];
  const float mu  = s * (1.0f / D);
  const float rs  = rsqrtf(s2 * (1.0f / D) - mu * mu + 1e-5f);
  const float mup = p * (1.0f / D);
  const float rsp = rsqrtf(p2 * (1.0f / D) - mup * mup + 1e-5f);
  u16x4 ok, ov, orr;
  #pragma unroll
  for (int i = 0; i < 4; ++i) {
    const int d = tid * 4 + i;
    const float h  = (v[i] - mu) * rs * g[d] + b[d];
    const float hp = first ? 0.0f : (vp[i] - mup) * rsp * g[d] + b[d];
    float a;
    a = mk[d]; ok[i]  = f2bf(h * a + hp * (1.0f - a));
    a = mv[d]; ov[i]  = f2bf(h * a + hp * (1.0f - a));
    a = mr[d]; orr[i] = f2bf(h * a + hp * (1.0f - a));
  }
  const size_t base = (size_t)m * D + tid * 4;
  *(u16x4*)&xk[base] = ok;
  *(u16x4*)&xv[base] = ov;
  *(u16x4*)&xr[base] = orr;
}

// ---------- fused LayerNorm + token-shift mix, 2 outputs (channel-mix) ----------
__global__ __launch_bounds__(256) void lnmix2_kernel(const float* __restrict__ x,
    const float* __restrict__ g, const float* __restrict__ b,
    const float* __restrict__ mk, const float* __restrict__ mr,
    u16* __restrict__ xk, u16* __restrict__ xr) {
  __shared__ float red[16];
  const int m = blockIdx.x, tid = threadIdx.x;
  const bool first = (m % T) == 0;
  f32x4 v = *(const f32x4*)&x[(size_t)m * D + tid * 4];
  f32x4 vp = {0.0f, 0.0f, 0.0f, 0.0f};
  if (!first) vp = *(const f32x4*)&x[(size_t)(m - 1) * D + tid * 4];
  float s  = v[0] + v[1] + v[2] + v[3];
  float s2 = v[0]*v[0] + v[1]*v[1] + v[2]*v[2] + v[3]*v[3];
  float p  = vp[0] + vp[1] + vp[2] + vp[3];
  float p2 = vp[0]*vp[0] + vp[1]*vp[1] + vp[2]*vp[2] + vp[3]*vp[3];
  #pragma unroll
  for (int o = 32; o > 0; o >>= 1) {
    s += __shfl_down(s, o); s2 += __shfl_down(s2, o);
    p += __shfl_down(p, o); p2 += __shfl_down(p2, o);
  }
  if ((tid & 63) == 0) {
    red[tid >> 6] = s; red[4 + (tid >> 6)] = s2;
    red[8 + (tid >> 6)] = p; red[12 + (tid >> 6)] = p2;
  }
  __syncthreads();
  s  = red[0] + red[1] + red[2] + red[3];
  s2 = red[4] + red[5] + red[6] + red[7];
  p  = red[8] + red[9] + red[10] + red[11];
  p2 = red[12] + red[13] + red[14] + red[15];
  const float mu  = s * (1.0f / D);
  const float rs  = rsqrtf(s2 * (1.0f / D) - mu * mu + 1e-5f);
  const float mup = p * (1.0f / D);
  const float rsp = rsqrtf(p2 * (1.0f / D) - mup * mup + 1e-5f);
  u16x4 ok, orr;
  #pragma unroll
  for (int i = 0; i < 4; ++i) {
    const int d = tid * 4 + i;
    const float h  = (v[i] - mu) * rs * g[d] + b[d];
    const float hp = first ? 0.0f : (vp[i] - mup) * rsp * g[d] + b[d];
    float a;
    a = mk[d]; ok[i]  = f2bf(h * a + hp * (1.0f - a));
    a = mr[d]; orr[i] = f2bf(h * a + hp * (1.0f - a));
  }
  const size_t base = (size_t)m * D + tid * 4;
  *(u16x4*)&xk[base] = ok;
  *(u16x4*)&xr[base] = orr;
}

// ---------- weight transpose + f32->bf16: in[K,N] f32 -> out[N,K] bf16 ----------
__global__ __launch_bounds__(256) void transpose_bf16_kernel(const float* __restrict__ in,
                                                             u16* __restrict__ out,
                                                             int K_, int N_) {
  __shared__ u16 t[32][33];
  const int k0 = blockIdx.x * 32, n0 = blockIdx.y * 32;
  const int r = threadIdx.x >> 5, c = threadIdx.x & 31;   // 8 x 32
  #pragma unroll
  for (int p = 0; p < 4; ++p)
    t[r + p * 8][c] = f2bf(in[(size_t)(k0 + r + p * 8) * N_ + n0 + c]);
  __syncthreads();
  #pragma unroll
  for (int p = 0; p < 4; ++p)
    out[(size_t)(n0 + r + p * 8) * K_ + k0 + c] = t[c][r + p * 8];
}

// ---------- chunk-parallel WKV scan (K bf16) ----------
__global__ __launch_bounds__(256) void wkv_phase1(const u16* __restrict__ K_,
                                                  const u16* __restrict__ V_,
                                                  const float* __restrict__ td,
                                                  float* __restrict__ aggA,
                                                  float* __restrict__ aggB,
                                                  float* __restrict__ aggP) {
  const int gid = blockIdx.x * 256 + threadIdx.x;   // ((b*NCH + c)*D + d)
  const int d = gid & (D - 1);
  const int c = (gid >> 10) & (NCH - 1);
  const int b = gid >> 15;
  const float w = -expf(td[d]);
  float a = 0.0f, bb = 0.0f, p = -1e38f;
  size_t idx = ((size_t)b * T + (size_t)c * CL) * D + d;
  for (int t = 0; t < CL; ++t, idx += D) {
    const float kt = bf2f(K_[idx]);
    const float vt = bf2f(V_[idx]);
    const float wp = p + w;
    const float pn = fmaxf(wp, kt);
    const float e1 = expf(wp - pn), e2 = expf(kt - pn);
    a  = e1 * a  + e2 * vt;
    bb = e1 * bb + e2;
    p  = pn;
  }
  aggA[gid] = a; aggB[gid] = bb; aggP[gid] = p;
}

__global__ __launch_bounds__(256) void wkv_phase2(const float* __restrict__ td,
                                                  const float* __restrict__ aggA,
                                                  const float* __restrict__ aggB,
                                                  const float* __restrict__ aggP,
                                                  float* __restrict__ incA,
                                                  float* __restrict__ incB,
                                                  float* __restrict__ incP) {
  const int gid = blockIdx.x * 256 + threadIdx.x;   // b*D + d
  const int d = gid & (D - 1);
  const int b = gid >> 10;
  const float cw = -expf(td[d]) * (float)CL;
  float a = 0.0f, bb = 0.0f, p = -1e38f;
  for (int c = 0; c < NCH; ++c) {
    const int i = (b * NCH + c) * D + d;
    incA[i] = a; incB[i] = bb; incP[i] = p;
    const float pd = p + cw;           // decay state across this chunk
    const float pc = aggP[i];
    const float pn = fmaxf(pd, pc);
    const float e1 = expf(pd - pn), e2 = expf(pc - pn);
    a  = e1 * a  + e2 * aggA[i];
    bb = e1 * bb + e2 * aggB[i];
    p  = pn;
  }
}

__global__ __launch_bounds__(256) void wkv_phase3(const u16* __restrict__ K_,
                                                  const u16* __restrict__ V_,
                                                  const u16* __restrict__ R_,
                                                  const float* __restrict__ td,
                                                  const float* __restrict__ tf,
                                                  const float* __restrict__ incA,
                                                  const float* __restrict__ incB,
                                                  const float* __restrict__ incP,
                                                  u16* __restrict__ a2) {
  const int gid = blockIdx.x * 256 + threadIdx.x;
  const int d = gid & (D - 1);
  const int c = (gid >> 10) & (NCH - 1);
  const int b = gid >> 15;
  const float w = -expf(td[d]);
  const float u = tf[d];
  float aa = incA[gid], bb = incB[gid], pp = incP[gid];
  size_t idx = ((size_t)b * T + (size_t)c * CL) * D + d;
  for (int t = 0; t < CL; ++t, idx += D) {
    const float kt = bf2f(K_[idx]);
    const float vt = bf2f(V_[idx]);
    const float rt = bf2f(R_[idx]);
    const float ww = u + kt;
    const float p  = fmaxf(pp, ww);
    const float e1 = expf(pp - p), e2 = expf(ww - p);
    const float o  = (e1 * aa + e2 * vt) / (e1 * bb + e2);
    a2[idx] = f2bf(rt * o);
    const float ww2 = pp + w;
    const float p2  = fmaxf(ww2, kt);
    const float e1b = expf(ww2 - p2), e2b = expf(kt - p2);
    aa = e1b * aa + e2b * vt;
    bb = e1b * bb + e2b;
    pp = p2;
  }
}

// ---------- 256x128 bf16 MFMA GEMM, BK=32, 3-buffer LDS, 2 blocks/CU ----------
// 8 waves (2M x 4N, wave tile 128x32), 72 KB LDS (3 bufs x {A 16K + B 8K}) ->
// 2 blocks/CU: inter-block TLP fills barrier/drain stalls (m114 mechanism).
// 2 phases/tile: {ds_read frags; stage buf (k+2)%3; barrier; lgkm0; sched_barrier;
// setprio; 8 MFMA; setprio; barrier}. vmcnt(3) per tile retires exactly tile
// k+1's 3 rounds (all >=2 phases old). Triple-buffer => stage writes never touch
// a buffer being read. Swizzle: slot ^= (row>>1)&3 (<=2-way on fragment reads).
// EPI: 0 f32 | 1 sigmoid->bf16 | 2 auxf+C->f32 | 3 relu(C)^2->bf16 | 4 dst+=bf16(auxh)*C | 5 bf16
template <int EPI>
__global__ __launch_bounds__(512, 4) void gemm8(const u16* __restrict__ A,
                                                const u16* __restrict__ Bt,
                                                int N, int K,
                                                float* __restrict__ outf,
                                                u16* __restrict__ outh,
                                                const float* __restrict__ auxf,
                                                const u16* __restrict__ auxh,
                                                float* __restrict__ dst) {
  __shared__ u16 sm[36864];           // 3 x {A[256][32] @0, B[128][32] @8192}
  const int gx = gridDim.x, gy = gridDim.y;
  const int fid = blockIdx.y * gx + blockIdx.x;
  const int xcd = fid & 7, sl = fid >> 3;
  const int m0 = (xcd * (gx >> 3) + sl / gy) * 256;   // XCD-stripe (gx%8==0)
  const int n0 = (sl % gy) * 128;

  const int tid = threadIdx.x;
  const int w = tid >> 6, l = tid & 63;
  const int wm = w >> 2, wn = w & 3;
  const int NT = K >> 5;              // BK=32
  f32x4 acc[8][2] = {};

  // staging: round = 128 rows; lane l covers row w*16+(l>>2), 16B slot l&3,
  // source col pre-swizzled (l&3)^((l>>3)&3)  [== slot ^ ((row>>1)&3)]
  const int srow = w * 16 + (l >> 2);
  const int scol = 8 * ((l & 3) ^ ((l >> 3) & 3));
  const u16* gA = A + (size_t)(m0 + srow) * K + scol;
  const u16* gB = Bt + (size_t)(n0 + srow) * K + scol;

  auto stA = [&](int j, int r) {
    gload16(gA + (size_t)r * 128 * K + (size_t)j * 32,
            &sm[(j % 3) * 12288 + (r * 128 + w * 16) * 32]);
  };
  auto stB = [&](int j) {
    gload16(gB + (size_t)j * 32,
            &sm[(j % 3) * 12288 + 8192 + (w * 16) * 32]);
  };

  u16x8 aF[4], bF[2];

#define LDB2(sBp)                                                           \
  _Pragma("unroll") for (int ni = 0; ni < 2; ++ni) {                        \
    const int rb = wn * 32 + ni * 16 + (l & 15);                            \
    const int rs = (l >> 4) ^ ((rb >> 1) & 3);                              \
    bF[ni] = *(const u16x8*)&sBp[rb * 32 + rs * 8];                         \
  }

#define LDA4(ph, sAp)                                                       \
  _Pragma("unroll") for (int qi = 0; qi < 4; ++qi) {                        \
    const int ra = wm * 128 + ((ph) * 4 + qi) * 16 + (l & 15);              \
    const int rs = (l >> 4) ^ ((ra >> 1) & 3);                              \
    aF[qi] = *(const u16x8*)&sAp[ra * 32 + rs * 8];                         \
  }

#define MFMA8(ph)                                                           \
  __builtin_amdgcn_s_setprio(1);                                            \
  _Pragma("unroll") for (int qi = 0; qi < 4; ++qi)                          \
    _Pragma("unroll") for (int ni = 0; ni < 2; ++ni)                        \
      acc[(ph) * 4 + qi][ni] = __builtin_amdgcn_mfma_f32_16x16x32_bf16(     \
          __builtin_bit_cast(bf16x8, aF[qi]),                               \
          __builtin_bit_cast(bf16x8, bF[ni]),                               \
          acc[(ph) * 4 + qi][ni], 0, 0, 0);                                 \
  __builtin_amdgcn_s_setprio(0);

#define LGKM0_FENCE                                                         \
  asm volatile("s_waitcnt lgkmcnt(0)" ::: "memory");                        \
  __builtin_amdgcn_sched_barrier(0);

  // prologue: stage tile0 + tile1 (3 rounds each)
  stB(0); stA(0, 0); stA(0, 1);
  if (1 < NT) {
    stB(1); stA(1, 0); stA(1, 1);
    asm volatile("s_waitcnt vmcnt(3)" ::: "memory");   // tile0 resident
  } else {
    asm volatile("s_waitcnt vmcnt(0)" ::: "memory");
  }
  __builtin_amdgcn_s_barrier();

  for (int k = 0; k < NT; ++k) {
    const u16* sA = &sm[(k % 3) * 12288];
    const u16* sB = sA + 8192;
    const bool s2 = (k + 2 < NT);
    // ---- phase 0: bF(2) + aF q0-3 (4) ----
    LDB2(sB);
    LDA4(0, sA);
    if (s2) { stB(k + 2); stA(k + 2, 0); }
    __builtin_amdgcn_s_barrier();
    LGKM0_FENCE
    MFMA8(0);
    __builtin_amdgcn_s_barrier();
    // ---- phase 1: aF q4-7 (4) ----
    LDA4(1, sA);
    if (s2) stA(k + 2, 1);
    __builtin_amdgcn_s_barrier();
    LGKM0_FENCE
    MFMA8(1);
    if (s2)      asm volatile("s_waitcnt vmcnt(3)" ::: "memory");  // tile k+1 landed
    else if (k + 1 < NT) asm volatile("s_waitcnt vmcnt(0)" ::: "memory");
    __builtin_amdgcn_s_barrier();
  }
#undef LDB2
#undef LDA4
#undef MFMA8
#undef LGKM0_FENCE

  const int cl = l & 15, rh = l >> 4;
  #pragma unroll
  for (int q = 0; q < 8; ++q) {
    #pragma unroll
    for (int ni = 0; ni < 2; ++ni) {
      const int gn = n0 + wn * 32 + ni * 16 + cl;
      #pragma unroll
      for (int j = 0; j < 4; ++j) {
        const int gm = m0 + wm * 128 + q * 16 + rh * 4 + j;
        const float c = acc[q][ni][j];
        const size_t o = (size_t)gm * N + gn;
        if (EPI == 0) outf[o] = c;
        else if (EPI == 1) outh[o] = f2bf(1.0f / (1.0f + expf(-c)));
        else if (EPI == 2) outf[o] = auxf[o] + c;
        else if (EPI == 3) { const float t = c > 0.0f ? c : 0.0f; outh[o] = f2bf(t * t); }
        else if (EPI == 4) dst[o] += bf2f(auxh[o]) * c;
        else if (EPI == 5) outh[o] = f2bf(c);
      }
    }
  }
}

extern "C" void kernel_launch(void* const* d_in, const int* in_sizes, int n_in,
                              void* d_out, int out_size, void* d_ws, size_t ws_size,
                              hipStream_t stream) {
  (void)in_sizes; (void)n_in; (void)out_size;
  const float* x      = (const float*)d_in[0];
  const float* ln1_g  = (const float*)d_in[1];
  const float* ln1_b  = (const float*)d_in[2];
  const float* ln2_g  = (const float*)d_in[3];
  const float* ln2_b  = (const float*)d_in[4];
  const float* tm_k   = (const float*)d_in[5];
  const float* tm_v   = (const float*)d_in[6];
  const float* tm_r   = (const float*)d_in[7];
  const float* tdec   = (const float*)d_in[8];
  const float* tfir   = (const float*)d_in[9];
  const float* wk     = (const float*)d_in[10];
  const float* wv     = (const float*)d_in[11];
  const float* wr     = (const float*)d_in[12];
  const float* wo     = (const float*)d_in[13];
  const float* cm_k   = (const float*)d_in[14];
  const float* cm_r   = (const float*)d_in[15];
  const float* cwk    = (const float*)d_in[16];
  const float* cwv    = (const float*)d_in[17];
  const float* cwr    = (const float*)d_in[18];
  float* out = (float*)d_out;

  const size_t MB = 1024 * 1024;
  if (ws_size < 218 * MB) return;   // diagnostic: leaves d_out poisoned

  char* w = (char*)d_ws;
  // region map (MB):
  u16*   h    = (u16*)(w);             // [0,32):  R -> rr
  u16*   b32  = (u16*)(w + 32 * MB);   // [32,64): xk -> V -> xck
  u16*   b64  = (u16*)(w + 64 * MB);   // [64,96): xv -> a2 -> xcr -> (KK head)
  u16*   b96  = (u16*)(w + 96 * MB);   // [96,128): xr -> scan scratch -> (KK)
  u16*   Kb   = (u16*)(w + 128 * MB);  // [128,160): K bf16 -> (KK tail)
  u16*   KK   = (u16*)(w + 64 * MB);   // [64,192): full M x FF bf16 (after deps dead)
  u16*   wkT  = (u16*)(w + 192 * MB);  // 2 MB each
  u16*   wvT  = (u16*)(w + 194 * MB);
  u16*   wrT  = (u16*)(w + 196 * MB);
  u16*   woT  = (u16*)(w + 198 * MB);
  u16*   cwkT = (u16*)(w + 200 * MB);  // 8 MB [FF,D]
  u16*   cwvT = (u16*)(w + 208 * MB);  // 8 MB [D,FF]
  u16*   cwrT = (u16*)(w + 216 * MB);  // 2 MB -> total 218 MB
  // scan scratch inside [96,128) (xr dead after R GEMM; KK written after scan):
  float* aggA = (float*)(w + 96 * MB);
  float* aggB = (float*)(w + 97 * MB);
  float* aggP = (float*)(w + 98 * MB);
  float* incA = (float*)(w + 99 * MB);
  float* incB = (float*)(w + 100 * MB);
  float* incP = (float*)(w + 101 * MB);

  // ---- weights: transpose + cast to bf16 ----
  transpose_bf16_kernel<<<dim3(D / 32, D / 32), 256, 0, stream>>>(wk, wkT, D, D);
  transpose_bf16_kernel<<<dim3(D / 32, D / 32), 256, 0, stream>>>(wv, wvT, D, D);
  transpose_bf16_kernel<<<dim3(D / 32, D / 32), 256, 0, stream>>>(wr, wrT, D, D);
  transpose_bf16_kernel<<<dim3(D / 32, D / 32), 256, 0, stream>>>(wo, woT, D, D);
  transpose_bf16_kernel<<<dim3(D / 32, FF / 32), 256, 0, stream>>>(cwk, cwkT, D, FF);
  transpose_bf16_kernel<<<dim3(FF / 32, D / 32), 256, 0, stream>>>(cwv, cwvT, FF, D);
  transpose_bf16_kernel<<<dim3(D / 32, D / 32), 256, 0, stream>>>(cwr, cwrT, D, D);

  // ---- time mixing (fused LN+mix) ----
  lnmix3_kernel<<<M, 256, 0, stream>>>(x, ln1_g, ln1_b, tm_k, tm_v, tm_r, b32, b64, b96);

  dim3 gD(M / 256, D / 128);      // (64, 8) -> 512 blocks, 2/CU
  // K = xk @ wk (bf16)
  gemm8<5><<<gD, 512, 0, stream>>>(b32, wkT, D, D, nullptr, Kb, nullptr, nullptr, nullptr);
  // V = xv @ wv (bf16) -> b32 (xk dead)
  gemm8<5><<<gD, 512, 0, stream>>>(b64, wvT, D, D, nullptr, b32, nullptr, nullptr, nullptr);
  // R = sigmoid(xr @ wr) (bf16) -> h
  gemm8<1><<<gD, 512, 0, stream>>>(b96, wrT, D, D, nullptr, h, nullptr, nullptr, nullptr);

  // chunk-parallel scan: a2 = bf16(r * wkv) -> b64 (xv dead)
  wkv_phase1<<<(NB * NCH * D) / 256, 256, 0, stream>>>(Kb, b32, tdec, aggA, aggB, aggP);
  wkv_phase2<<<(NB * D) / 256, 256, 0, stream>>>(tdec, aggA, aggB, aggP, incA, incB, incP);
  wkv_phase3<<<(NB * NCH * D) / 256, 256, 0, stream>>>(Kb, b32, h, tdec, tfir,
                                                       incA, incB, incP, b64);

  // out = x + a2 @ wo
  gemm8<2><<<gD, 512, 0, stream>>>(b64, woT, D, D, out, nullptr, x, nullptr, nullptr);

  // ---- channel mixing (fused LN+mix) ----
  lnmix2_kernel<<<M, 256, 0, stream>>>(out, ln2_g, ln2_b, cm_k, cm_r, b32, b64); // xck, xcr

  // rr = sigmoid(xcr @ cwr) (bf16) -> h (R dead)
  gemm8<1><<<gD, 512, 0, stream>>>(b64, cwrT, D, D, nullptr, h, nullptr, nullptr, nullptr);

  // KK = relu(xck @ cwk)^2 (bf16) -> [64,192) (xcr/scratch/Kb all dead)
  dim3 gF(M / 256, FF / 128);     // (64, 32)
  gemm8<3><<<gF, 512, 0, stream>>>(b32, cwkT, FF, D, nullptr, KK, nullptr, nullptr, nullptr);

  // out += rr * (KK @ cwv)
  dim3 gO(M / 256, D / 128);      // (64, 8), K = FF
  gemm8<4><<<gO, 512, 0, stream>>>(KK, cwvT, D, FF, nullptr, nullptr, nullptr, h, out);
}

// Round 13
// 726.695 us; speedup vs baseline: 1.0238x; 1.0238x over previous
//
#include <hip/hip_runtime.h>

typedef unsigned short u16;
typedef float f32x2 __attribute__((ext_vector_type(2)));
typedef float f32x4 __attribute__((ext_vector_type(4)));
typedef __bf16 bf16x8 __attribute__((ext_vector_type(8)));
typedef u16 u16x2 __attribute__((ext_vector_type(2)));
typedef u16 u16x8 __attribute__((ext_vector_type(8)));
typedef u16 u16x4 __attribute__((ext_vector_type(4)));

static constexpr int D  = 1024;
static constexpr int T  = 2048;
static constexpr int NB = 8;            // batch
static constexpr int M  = NB * T;       // 16384 rows
static constexpr int FF = 4096;
static constexpr int NCH = 64;          // scan chunks per sequence
static constexpr int CL  = T / NCH;     // 32 steps per chunk

__device__ __forceinline__ u16 f2bf(float f) {
  unsigned u = __builtin_bit_cast(unsigned, f);
  return (u16)((u + 0x7fffu + ((u >> 16) & 1u)) >> 16);   // RNE
}
__device__ __forceinline__ float bf2f(u16 s) {
  return __builtin_bit_cast(float, (unsigned)s << 16);
}

// async global->LDS 16B: LDS dest is wave-uniform base + lane*16 (m104);
// swizzling is done by pre-swizzling the per-lane GLOBAL address (m173).
__device__ __forceinline__ void gload16(const u16* g, u16* l) {
  __builtin_amdgcn_global_load_lds(
      (const __attribute__((address_space(1))) void*)g,
      (__attribute__((address_space(3))) void*)l, 16, 0, 0);
}

// ---------- fused LayerNorm + token-shift mix, 3 outputs (time-mix) ----------
__global__ __launch_bounds__(256) void lnmix3_kernel(const float* __restrict__ x,
    const float* __restrict__ g, const float* __restrict__ b,
    const float* __restrict__ mk, const float* __restrict__ mv, const float* __restrict__ mr,
    u16* __restrict__ xk, u16* __restrict__ xv, u16* __restrict__ xr) {
  __shared__ float red[16];
  const int m = blockIdx.x, tid = threadIdx.x;
  const bool first = (m % T) == 0;
  f32x4 v = *(const f32x4*)&x[(size_t)m * D + tid * 4];
  f32x4 vp = {0.0f, 0.0f, 0.0f, 0.0f};
  if (!first) vp = *(const f32x4*)&x[(size_t)(m - 1) * D + tid * 4];
  float s  = v[0] + v[1] + v[2] + v[3];
  float s2 = v[0]*v[0] + v[1]*v[1] + v[2]*v[2] + v[3]*v[3];
  float p  = vp[0] + vp[1] + vp[2] + vp[3];
  float p2 = vp[0]*vp[0] + vp[1]*vp[1] + vp[2]*vp[2] + vp[3]*vp[3];
  #pragma unroll
  for (int o = 32; o > 0; o >>= 1) {
    s += __shfl_down(s, o); s2 += __shfl_down(s2, o);
    p += __shfl_down(p, o); p2 += __shfl_down(p2, o);
  }
  if ((tid & 63) == 0) {
    red[tid >> 6] = s; red[4 + (tid >> 6)] = s2;
    red[8 + (tid >> 6)] = p; red[12 + (tid >> 6)] = p2;
  }
  __syncthreads();
  s  = red[0] + red[1] + red[2] + red[3];
  s2 = red[4] + red[5] + red[6] + red[7];
  p  = red[8] + red[9] + red[10] + red[11];
  p2 = red[12] + red[13] + red[14] + red[15];
  const float mu  = s * (1.0f / D);
  const float rs  = rsqrtf(s2 * (1.0f / D) - mu * mu + 1e-5f);
  const float mup = p * (1.0f / D);
  const float rsp = rsqrtf(p2 * (1.0f / D) - mup * mup + 1e-5f);
  u16x4 ok, ov, orr;
  #pragma unroll
  for (int i = 0; i < 4; ++i) {
    const int d = tid * 4 + i;
    const float h  = (v[i] - mu) * rs * g[d] + b[d];
    const float hp = first ? 0.0f : (vp[i] - mup) * rsp * g[d] + b[d];
    float a;
    a = mk[d]; ok[i]  = f2bf(h * a + hp * (1.0f - a));
    a = mv[d]; ov[i]  = f2bf(h * a + hp * (1.0f - a));
    a = mr[d]; orr[i] = f2bf(h * a + hp * (1.0f - a));
  }
  const size_t base = (size_t)m * D + tid * 4;
  *(u16x4*)&xk[base] = ok;
  *(u16x4*)&xv[base] = ov;
  *(u16x4*)&xr[base] = orr;
}

// ---------- fused LayerNorm + token-shift mix, 2 outputs (channel-mix) ----------
__global__ __launch_bounds__(256) void lnmix2_kernel(const float* __restrict__ x,
    const float* __restrict__ g, const float* __restrict__ b,
    const float* __restrict__ mk, const float* __restrict__ mr,
    u16* __restrict__ xk, u16* __restrict__ xr) {
  __shared__ float red[16];
  const int m = blockIdx.x, tid = threadIdx.x;
  const bool first = (m % T) == 0;
  f32x4 v = *(const f32x4*)&x[(size_t)m * D + tid * 4];
  f32x4 vp = {0.0f, 0.0f, 0.0f, 0.0f};
  if (!first) vp = *(const f32x4*)&x[(size_t)(m - 1) * D + tid * 4];
  float s  = v[0] + v[1] + v[2] + v[3];
  float s2 = v[0]*v[0] + v[1]*v[1] + v[2]*v[2] + v[3]*v[3];
  float p  = vp[0] + vp[1] + vp[2] + vp[3];
  float p2 = vp[0]*vp[0] + vp[1]*vp[1] + vp[2]*vp[2] + vp[3]*vp[3];
  #pragma unroll
  for (int o = 32; o > 0; o >>= 1) {
    s += __shfl_down(s, o); s2 += __shfl_down(s2, o);
    p += __shfl_down(p, o); p2 += __shfl_down(p2, o);
  }
  if ((tid & 63) == 0) {
    red[tid >> 6] = s; red[4 + (tid >> 6)] = s2;
    red[8 + (tid >> 6)] = p; red[12 + (tid >> 6)] = p2;
  }
  __syncthreads();
  s  = red[0] + red[1] + red[2] + red[3];
  s2 = red[4] + red[5] + red[6] + red[7];
  p  = red[8] + red[9] + red[10] + red[11];
  p2 = red[12] + red[13] + red[14] + red[15];
  const float mu  = s * (1.0f / D);
  const float rs  = rsqrtf(s2 * (1.0f / D) - mu * mu + 1e-5f);
  const float mup = p * (1.0f / D);
  const float rsp = rsqrtf(p2 * (1.0f / D) - mup * mup + 1e-5f);
  u16x4 ok, orr;
  #pragma unroll
  for (int i = 0; i < 4; ++i) {
    const int d = tid * 4 + i;
    const float h  = (v[i] - mu) * rs * g[d] + b[d];
    const float hp = first ? 0.0f : (vp[i] - mup) * rsp * g[d] + b[d];
    float a;
    a = mk[d]; ok[i]  = f2bf(h * a + hp * (1.0f - a));
    a = mr[d]; orr[i] = f2bf(h * a + hp * (1.0f - a));
  }
  const size_t base = (size_t)m * D + tid * 4;
  *(u16x4*)&xk[base] = ok;
  *(u16x4*)&xr[base] = orr;
}

// ---------- batched weight transpose + f32->bf16 (4x DxD in one launch) ----------
__global__ __launch_bounds__(256) void transpose4_kernel(
    const float* __restrict__ i0, const float* __restrict__ i1,
    const float* __restrict__ i2, const float* __restrict__ i3,
    u16* __restrict__ o0, u16* __restrict__ o1,
    u16* __restrict__ o2, u16* __restrict__ o3) {
  __shared__ u16 t[32][33];
  const float* in;
  u16* out;
  switch (blockIdx.z) {
    case 0:  in = i0; out = o0; break;
    case 1:  in = i1; out = o1; break;
    case 2:  in = i2; out = o2; break;
    default: in = i3; out = o3; break;
  }
  const int k0 = blockIdx.x * 32, n0 = blockIdx.y * 32;
  const int r = threadIdx.x >> 5, c = threadIdx.x & 31;   // 8 x 32
  #pragma unroll
  for (int p = 0; p < 4; ++p)
    t[r + p * 8][c] = f2bf(in[(size_t)(k0 + r + p * 8) * D + n0 + c]);
  __syncthreads();
  #pragma unroll
  for (int p = 0; p < 4; ++p)
    out[(size_t)(n0 + r + p * 8) * D + k0 + c] = t[c][r + p * 8];
}

// ---------- generic transpose (cwk/cwv rectangular) ----------
__global__ __launch_bounds__(256) void transpose_bf16_kernel(const float* __restrict__ in,
                                                             u16* __restrict__ out,
                                                             int K_, int N_) {
  __shared__ u16 t[32][33];
  const int k0 = blockIdx.x * 32, n0 = blockIdx.y * 32;
  const int r = threadIdx.x >> 5, c = threadIdx.x & 31;   // 8 x 32
  #pragma unroll
  for (int p = 0; p < 4; ++p)
    t[r + p * 8][c] = f2bf(in[(size_t)(k0 + r + p * 8) * N_ + n0 + c]);
  __syncthreads();
  #pragma unroll
  for (int p = 0; p < 4; ++p)
    out[(size_t)(n0 + r + p * 8) * K_ + k0 + c] = t[c][r + p * 8];
}

// ---------- chunk-parallel WKV scan, x2-vectorized (d-pairs, u16x2/f32x2) ----------
__global__ __launch_bounds__(256) void wkv_phase1(const u16* __restrict__ K_,
                                                  const u16* __restrict__ V_,
                                                  const float* __restrict__ td,
                                                  float* __restrict__ aggA,
                                                  float* __restrict__ aggB,
                                                  float* __restrict__ aggP) {
  const int gid = blockIdx.x * 256 + threadIdx.x;   // 0 .. NB*NCH*D/2
  const int d = (gid & (D / 2 - 1)) * 2;
  const int c = (gid >> 9) & (NCH - 1);
  const int b = gid >> 15;
  const f32x2 tdv = *(const f32x2*)&td[d];
  const float w0 = -expf(tdv[0]), w1 = -expf(tdv[1]);
  float a0 = 0.0f, b0 = 0.0f, p0 = -1e38f;
  float a1 = 0.0f, b1 = 0.0f, p1 = -1e38f;
  size_t idx = ((size_t)b * T + (size_t)c * CL) * D + d;
  for (int t = 0; t < CL; ++t, idx += D) {
    const u16x2 kv = *(const u16x2*)&K_[idx];
    const u16x2 vv = *(const u16x2*)&V_[idx];
    {
      const float kt = bf2f(kv[0]), vt = bf2f(vv[0]);
      const float wp = p0 + w0;
      const float pn = fmaxf(wp, kt);
      const float e1 = expf(wp - pn), e2 = expf(kt - pn);
      a0 = e1 * a0 + e2 * vt; b0 = e1 * b0 + e2; p0 = pn;
    }
    {
      const float kt = bf2f(kv[1]), vt = bf2f(vv[1]);
      const float wp = p1 + w1;
      const float pn = fmaxf(wp, kt);
      const float e1 = expf(wp - pn), e2 = expf(kt - pn);
      a1 = e1 * a1 + e2 * vt; b1 = e1 * b1 + e2; p1 = pn;
    }
  }
  const size_t o = (size_t)(b * NCH + c) * D + d;
  *(f32x2*)&aggA[o] = f32x2{a0, a1};
  *(f32x2*)&aggB[o] = f32x2{b0, b1};
  *(f32x2*)&aggP[o] = f32x2{p0, p1};
}

__global__ __launch_bounds__(256) void wkv_phase2(const float* __restrict__ td,
                                                  const float* __restrict__ aggA,
                                                  const float* __restrict__ aggB,
                                                  const float* __restrict__ aggP,
                                                  float* __restrict__ incA,
                                                  float* __restrict__ incB,
                                                  float* __restrict__ incP) {
  const int gid = blockIdx.x * 256 + threadIdx.x;   // 0 .. NB*D/2
  const int d = (gid & (D / 2 - 1)) * 2;
  const int b = gid >> 9;
  const f32x2 tdv = *(const f32x2*)&td[d];
  const float cw0 = -expf(tdv[0]) * (float)CL;
  const float cw1 = -expf(tdv[1]) * (float)CL;
  float a0 = 0.0f, b0 = 0.0f, p0 = -1e38f;
  float a1 = 0.0f, b1 = 0.0f, p1 = -1e38f;
  for (int c = 0; c < NCH; ++c) {
    const size_t i = (size_t)(b * NCH + c) * D + d;
    *(f32x2*)&incA[i] = f32x2{a0, a1};
    *(f32x2*)&incB[i] = f32x2{b0, b1};
    *(f32x2*)&incP[i] = f32x2{p0, p1};
    const f32x2 ga = *(const f32x2*)&aggA[i];
    const f32x2 gb = *(const f32x2*)&aggB[i];
    const f32x2 gp = *(const f32x2*)&aggP[i];
    {
      const float pd = p0 + cw0;
      const float pn = fmaxf(pd, gp[0]);
      const float e1 = expf(pd - pn), e2 = expf(gp[0] - pn);
      a0 = e1 * a0 + e2 * ga[0]; b0 = e1 * b0 + e2 * gb[0]; p0 = pn;
    }
    {
      const float pd = p1 + cw1;
      const float pn = fmaxf(pd, gp[1]);
      const float e1 = expf(pd - pn), e2 = expf(gp[1] - pn);
      a1 = e1 * a1 + e2 * ga[1]; b1 = e1 * b1 + e2 * gb[1]; p1 = pn;
    }
  }
}

__global__ __launch_bounds__(256) void wkv_phase3(const u16* __restrict__ K_,
                                                  const u16* __restrict__ V_,
                                                  const u16* __restrict__ R_,
                                                  const float* __restrict__ td,
                                                  const float* __restrict__ tf,
                                                  const float* __restrict__ incA,
                                                  const float* __restrict__ incB,
                                                  const float* __restrict__ incP,
                                                  u16* __restrict__ a2) {
  const int gid = blockIdx.x * 256 + threadIdx.x;
  const int d = (gid & (D / 2 - 1)) * 2;
  const int c = (gid >> 9) & (NCH - 1);
  const int b = gid >> 15;
  const f32x2 tdv = *(const f32x2*)&td[d];
  const f32x2 tfv = *(const f32x2*)&tf[d];
  const float w0 = -expf(tdv[0]), w1 = -expf(tdv[1]);
  const float u0 = tfv[0], u1 = tfv[1];
  const size_t si = (size_t)(b * NCH + c) * D + d;
  f32x2 iA = *(const f32x2*)&incA[si];
  f32x2 iB = *(const f32x2*)&incB[si];
  f32x2 iP = *(const f32x2*)&incP[si];
  float aa0 = iA[0], bb0 = iB[0], pp0 = iP[0];
  float aa1 = iA[1], bb1 = iB[1], pp1 = iP[1];
  size_t idx = ((size_t)b * T + (size_t)c * CL) * D + d;
  for (int t = 0; t < CL; ++t, idx += D) {
    const u16x2 kv = *(const u16x2*)&K_[idx];
    const u16x2 vv = *(const u16x2*)&V_[idx];
    const u16x2 rv = *(const u16x2*)&R_[idx];
    u16x2 ov;
    {
      const float kt = bf2f(kv[0]), vt = bf2f(vv[0]), rt = bf2f(rv[0]);
      const float ww = u0 + kt;
      const float p  = fmaxf(pp0, ww);
      const float e1 = expf(pp0 - p), e2 = expf(ww - p);
      ov[0] = f2bf(rt * ((e1 * aa0 + e2 * vt) / (e1 * bb0 + e2)));
      const float ww2 = pp0 + w0;
      const float p2  = fmaxf(ww2, kt);
      const float e1b = expf(ww2 - p2), e2b = expf(kt - p2);
      aa0 = e1b * aa0 + e2b * vt; bb0 = e1b * bb0 + e2b; pp0 = p2;
    }
    {
      const float kt = bf2f(kv[1]), vt = bf2f(vv[1]), rt = bf2f(rv[1]);
      const float ww = u1 + kt;
      const float p  = fmaxf(pp1, ww);
      const float e1 = expf(pp1 - p), e2 = expf(ww - p);
      ov[1] = f2bf(rt * ((e1 * aa1 + e2 * vt) / (e1 * bb1 + e2)));
      const float ww2 = pp1 + w1;
      const float p2  = fmaxf(ww2, kt);
      const float e1b = expf(ww2 - p2), e2b = expf(kt - p2);
      aa1 = e1b * aa1 + e2b * vt; bb1 = e1b * bb1 + e2b; pp1 = p2;
    }
    *(u16x2*)&a2[idx] = ov;
  }
}

// ---------- 256x256 bf16 MFMA GEMM — m201 8-phase skeleton (r11, best) ----------
// 8 waves (2M x 4N), BK=64, 128KB LDS dbuf, 16x16x32 MFMA. Per phase:
//   {ds_read this phase's frags; stage gloads; [lgkmcnt(8) if 12 reads];
//    s_barrier; lgkmcnt(0); sched_barrier(0); setprio(1); 16 MFMA; setprio(0); s_barrier}
// vmcnt(6) once per K-tile at phase 3. Stage rows disjoint from unretired reads.
// EPI: 0 f32 | 1 sigmoid->bf16 | 2 auxf+C->f32 | 3 relu(C)^2->bf16 | 4 dst+=bf16(auxh)*C | 5 bf16
template <int EPI>
__global__ __launch_bounds__(512, 2) void gemm8(const u16* __restrict__ A,
                                                const u16* __restrict__ Bt,
                                                int N, int K,
                                                float* __restrict__ outf,
                                                u16* __restrict__ outh,
                                                const float* __restrict__ auxf,
                                                const u16* __restrict__ auxh,
                                                float* __restrict__ dst) {
  __shared__ u16 sm[65536];           // [0,32768): A bufs, [32768,65536): B bufs
  const int gx = gridDim.x, gy = gridDim.y;
  const int fid = blockIdx.y * gx + blockIdx.x;
  const int xcd = fid & 7, sl = fid >> 3;
  const int m0 = (xcd * (gx >> 3) + sl / gy) * 256;   // XCD-stripe mapping (gx%8==0)
  const int n0 = (sl % gy) * 256;

  const int tid = threadIdx.x;
  const int w = tid >> 6, l = tid & 63;
  const int wm = w >> 2, wn = w & 3;
  const int lr = l >> 3, ls = l & 7;
  const int NT = K >> 6;
  f32x4 acc[8][4] = {};

  const u16* gA = A + (size_t)(m0 + w * 8 + lr) * K + (ls ^ lr) * 8;
  const u16* gB = Bt + (size_t)(n0 + w * 8 + lr) * K + (ls ^ lr) * 8;

  auto stA = [&](int j, int r) {
    gload16(gA + ((size_t)r * 64) * K + (size_t)j * 64,
            &sm[(j & 1) * 16384 + (r * 64 + w * 8) * 64]);
  };
  auto stB = [&](int j, int r) {
    gload16(gB + ((size_t)r * 64) * K + (size_t)j * 64,
            &sm[32768 + (j & 1) * 16384 + (r * 64 + w * 8) * 64]);
  };

  u16x8 bF[4][2], aF[2][2];

  auto ldB8 = [&](const u16* sB) {
    #pragma unroll
    for (int ni = 0; ni < 4; ++ni)
      #pragma unroll
      for (int ks = 0; ks < 2; ++ks) {
        const int rb = wn * 64 + ni * 16 + (l & 15);
        const int rs = ks * 4 + (l >> 4);
        bF[ni][ks] = *(const u16x8*)&sB[rb * 64 + ((rs ^ (rb & 7)) * 8)];
      }
  };

#define LDA(q, sAp)                                                         \
  _Pragma("unroll") for (int mi = 0; mi < 2; ++mi)                          \
    _Pragma("unroll") for (int ks = 0; ks < 2; ++ks) {                      \
      const int ra = wm * 128 + (q) * 32 + mi * 16 + (l & 15);              \
      const int rs = ks * 4 + (l >> 4);                                     \
      aF[mi][ks] = *(const u16x8*)&sAp[ra * 64 + ((rs ^ (ra & 7)) * 8)];    \
    }

#define MFMA16(Q)                                                           \
  __builtin_amdgcn_s_setprio(1);                                            \
  _Pragma("unroll") for (int ks = 0; ks < 2; ++ks)                          \
    _Pragma("unroll") for (int mi = 0; mi < 2; ++mi)                        \
      _Pragma("unroll") for (int ni = 0; ni < 4; ++ni)                      \
        acc[(Q) * 2 + mi][ni] = __builtin_amdgcn_mfma_f32_16x16x32_bf16(    \
            __builtin_bit_cast(bf16x8, aF[mi][ks]),                         \
            __builtin_bit_cast(bf16x8, bF[ni][ks]),                         \
            acc[(Q) * 2 + mi][ni], 0, 0, 0);                                \
  __builtin_amdgcn_s_setprio(0);

#define LGKM0_FENCE                                                         \
  asm volatile("s_waitcnt lgkmcnt(0)" ::: "memory");                        \
  __builtin_amdgcn_sched_barrier(0);

  // prologue: tile0 fully (8 rounds), then tile1 fully (8 rounds)
  stB(0, 0); stB(0, 1); stB(0, 2); stB(0, 3);
  stA(0, 0); stA(0, 1); stA(0, 2); stA(0, 3);
  if (1 < NT) {
    stB(1, 0); stB(1, 1); stB(1, 2); stB(1, 3);
    stA(1, 0); stA(1, 1); stA(1, 2); stA(1, 3);
    asm volatile("s_waitcnt vmcnt(8)" ::: "memory");   // tile0 resident; tile1 in flight
  } else {
    asm volatile("s_waitcnt vmcnt(0)" ::: "memory");
  }
  __builtin_amdgcn_s_barrier();

  for (int k = 0; k < NT; ++k) {
    const u16* sA = &sm[(k & 1) * 16384];
    const u16* sB = &sm[32768 + (k & 1) * 16384];
    const bool s2 = (k + 2 < NT);
    // ---- phase 0: bF(8) + aF0(4) reads ----
    ldB8(sB);
    LDA(0, sA);
    asm volatile("s_waitcnt lgkmcnt(8)" ::: "memory");   // stagger (12-read phase)
    __builtin_amdgcn_s_barrier();
    LGKM0_FENCE
    MFMA16(0);
    __builtin_amdgcn_s_barrier();
    // ---- phase 1 ----
    LDA(1, sA);
    if (s2) { stB(k + 2, 0); stB(k + 2, 1); }
    __builtin_amdgcn_s_barrier();
    LGKM0_FENCE
    MFMA16(1);
    __builtin_amdgcn_s_barrier();
    // ---- phase 2 ----
    LDA(2, sA);
    if (s2) { stB(k + 2, 2); stB(k + 2, 3); stA(k + 2, 0); stA(k + 2, 2); }
    __builtin_amdgcn_s_barrier();
    LGKM0_FENCE
    MFMA16(2);
    __builtin_amdgcn_s_barrier();
    // ---- phase 3: stage A r1,r3 after drain (aF3 retired); counted vmcnt ----
    LDA(3, sA);
    __builtin_amdgcn_s_barrier();
    LGKM0_FENCE
    if (s2) {
      stA(k + 2, 1); stA(k + 2, 3);
      asm volatile("s_waitcnt vmcnt(6)" ::: "memory");   // all of tile k+1 retired
    } else if (k + 1 < NT) {
      asm volatile("s_waitcnt vmcnt(0)" ::: "memory");
    }
    MFMA16(3);
    __builtin_amdgcn_s_barrier();
  }
#undef LDA
#undef MFMA16
#undef LGKM0_FENCE

  const int cl = l & 15, rh = l >> 4;
  #pragma unroll
  for (int mi = 0; mi < 8; ++mi) {
    #pragma unroll
    for (int ni = 0; ni < 4; ++ni) {
      const int gn = n0 + wn * 64 + ni * 16 + cl;
      #pragma unroll
      for (int j = 0; j < 4; ++j) {
        const int gm = m0 + wm * 128 + mi * 16 + rh * 4 + j;
        const float c = acc[mi][ni][j];
        const size_t o = (size_t)gm * N + gn;
        if (EPI == 0) outf[o] = c;
        else if (EPI == 1) outh[o] = f2bf(1.0f / (1.0f + expf(-c)));
        else if (EPI == 2) outf[o] = auxf[o] + c;
        else if (EPI == 3) { const float t = c > 0.0f ? c : 0.0f; outh[o] = f2bf(t * t); }
        else if (EPI == 4) dst[o] += bf2f(auxh[o]) * c;
        else if (EPI == 5) outh[o] = f2bf(c);
      }
    }
  }
}

extern "C" void kernel_launch(void* const* d_in, const int* in_sizes, int n_in,
                              void* d_out, int out_size, void* d_ws, size_t ws_size,
                              hipStream_t stream) {
  (void)in_sizes; (void)n_in; (void)out_size;
  const float* x      = (const float*)d_in[0];
  const float* ln1_g  = (const float*)d_in[1];
  const float* ln1_b  = (const float*)d_in[2];
  const float* ln2_g  = (const float*)d_in[3];
  const float* ln2_b  = (const float*)d_in[4];
  const float* tm_k   = (const float*)d_in[5];
  const float* tm_v   = (const float*)d_in[6];
  const float* tm_r   = (const float*)d_in[7];
  const float* tdec   = (const float*)d_in[8];
  const float* tfir   = (const float*)d_in[9];
  const float* wk     = (const float*)d_in[10];
  const float* wv     = (const float*)d_in[11];
  const float* wr     = (const float*)d_in[12];
  const float* wo     = (const float*)d_in[13];
  const float* cm_k   = (const float*)d_in[14];
  const float* cm_r   = (const float*)d_in[15];
  const float* cwk    = (const float*)d_in[16];
  const float* cwv    = (const float*)d_in[17];
  const float* cwr    = (const float*)d_in[18];
  float* out = (float*)d_out;

  const size_t MB = 1024 * 1024;
  if (ws_size < 218 * MB) return;   // diagnostic: leaves d_out poisoned

  char* w = (char*)d_ws;
  // region map (MB):
  u16*   h    = (u16*)(w);             // [0,32):  R -> rr
  u16*   b32  = (u16*)(w + 32 * MB);   // [32,64): xk -> V -> xck
  u16*   b64  = (u16*)(w + 64 * MB);   // [64,96): xv -> a2 -> xcr -> (KK head)
  u16*   b96  = (u16*)(w + 96 * MB);   // [96,128): xr -> scan scratch -> (KK)
  u16*   Kb   = (u16*)(w + 128 * MB);  // [128,160): K bf16 -> (KK tail)
  u16*   KK   = (u16*)(w + 64 * MB);   // [64,192): full M x FF bf16 (after deps dead)
  u16*   wkT  = (u16*)(w + 192 * MB);  // 2 MB each
  u16*   wvT  = (u16*)(w + 194 * MB);
  u16*   wrT  = (u16*)(w + 196 * MB);
  u16*   woT  = (u16*)(w + 198 * MB);
  u16*   cwkT = (u16*)(w + 200 * MB);  // 8 MB [FF,D]
  u16*   cwvT = (u16*)(w + 208 * MB);  // 8 MB [D,FF]
  u16*   cwrT = (u16*)(w + 216 * MB);  // 2 MB -> total 218 MB
  // scan scratch inside [96,128): NCH=64 -> 2 MB per array, 12 MB total
  float* aggA = (float*)(w + 96 * MB);
  float* aggB = (float*)(w + 98 * MB);
  float* aggP = (float*)(w + 100 * MB);
  float* incA = (float*)(w + 102 * MB);
  float* incB = (float*)(w + 104 * MB);
  float* incP = (float*)(w + 106 * MB);

  // ---- weights: transpose + cast to bf16 ----
  transpose4_kernel<<<dim3(D / 32, D / 32, 4), 256, 0, stream>>>(
      wk, wv, wr, wo, wkT, wvT, wrT, woT);
  transpose_bf16_kernel<<<dim3(D / 32, FF / 32), 256, 0, stream>>>(cwk, cwkT, D, FF);
  transpose_bf16_kernel<<<dim3(FF / 32, D / 32), 256, 0, stream>>>(cwv, cwvT, FF, D);
  transpose_bf16_kernel<<<dim3(D / 32, D / 32), 256, 0, stream>>>(cwr, cwrT, D, D);

  // ---- time mixing (fused LN+mix) ----
  lnmix3_kernel<<<M, 256, 0, stream>>>(x, ln1_g, ln1_b, tm_k, tm_v, tm_r, b32, b64, b96);

  dim3 gD(M / 256, D / 256);      // (64, 4)
  // K = xk @ wk (bf16)
  gemm8<5><<<gD, 512, 0, stream>>>(b32, wkT, D, D, nullptr, Kb, nullptr, nullptr, nullptr);
  // V = xv @ wv (bf16) -> b32 (xk dead)
  gemm8<5><<<gD, 512, 0, stream>>>(b64, wvT, D, D, nullptr, b32, nullptr, nullptr, nullptr);
  // R = sigmoid(xr @ wr) (bf16) -> h
  gemm8<1><<<gD, 512, 0, stream>>>(b96, wrT, D, D, nullptr, h, nullptr, nullptr, nullptr);

  // chunk-parallel scan (x2 vectorized): a2 = bf16(r * wkv) -> b64 (xv dead)
  wkv_phase1<<<(NB * NCH * D / 2) / 256, 256, 0, stream>>>(Kb, b32, tdec, aggA, aggB, aggP);
  wkv_phase2<<<(NB * D / 2) / 256, 256, 0, stream>>>(tdec, aggA, aggB, aggP, incA, incB, incP);
  wkv_phase3<<<(NB * NCH * D / 2) / 256, 256, 0, stream>>>(Kb, b32, h, tdec, tfir,
                                                           incA, incB, incP, b64);

  // out = x + a2 @ wo
  gemm8<2><<<gD, 512, 0, stream>>>(b64, woT, D, D, out, nullptr, x, nullptr, nullptr);

  // ---- channel mixing (fused LN+mix) ----
  lnmix2_kernel<<<M, 256, 0, stream>>>(out, ln2_g, ln2_b, cm_k, cm_r, b32, b64); // xck, xcr

  // rr = sigmoid(xcr @ cwr) (bf16) -> h (R dead)
  gemm8<1><<<gD, 512, 0, stream>>>(b64, cwrT, D, D, nullptr, h, nullptr, nullptr, nullptr);

  // KK = relu(xck @ cwk)^2 (bf16) -> [64,192) (xcr/scratch/Kb all dead)
  dim3 gF(M / 256, FF / 256);     // (64, 16)
  gemm8<3><<<gF, 512, 0, stream>>>(b32, cwkT, FF, D, nullptr, KK, nullptr, nullptr, nullptr);

  // out += rr * (KK @ cwv)
  dim3 gO(M / 256, D / 256);      // (64, 4), K = FF
  gemm8<4><<<gO, 512, 0, stream>>>(KK, cwvT, D, FF, nullptr, nullptr, nullptr, h, out);
}

// Round 14
// 709.307 us; speedup vs baseline: 1.0489x; 1.0245x over previous
//
#include <hip/hip_runtime.h>

typedef unsigned short u16;
typedef float f32x4 __attribute__((ext_vector_type(4)));
typedef __bf16 bf16x8 __attribute__((ext_vector_type(8)));
typedef u16 u16x8 __attribute__((ext_vector_type(8)));
typedef u16 u16x4 __attribute__((ext_vector_type(4)));

static constexpr int D  = 1024;
static constexpr int T  = 2048;
static constexpr int NB = 8;            // batch
static constexpr int M  = NB * T;       // 16384 rows
static constexpr int FF = 4096;
static constexpr int NCH = 32;          // scan chunks per sequence
static constexpr int CL  = T / NCH;     // 64 steps per chunk

__device__ __forceinline__ u16 f2bf(float f) {
  unsigned u = __builtin_bit_cast(unsigned, f);
  return (u16)((u + 0x7fffu + ((u >> 16) & 1u)) >> 16);   // RNE
}
__device__ __forceinline__ float bf2f(u16 s) {
  return __builtin_bit_cast(float, (unsigned)s << 16);
}

// async global->LDS 16B: LDS dest is wave-uniform base + lane*16 (m104);
// swizzling is done by pre-swizzling the per-lane GLOBAL address (m173).
__device__ __forceinline__ void gload16(const u16* g, u16* l) {
  __builtin_amdgcn_global_load_lds(
      (const __attribute__((address_space(1))) void*)g,
      (__attribute__((address_space(3))) void*)l, 16, 0, 0);
}

// ---------- fused LayerNorm + token-shift mix, 3 outputs (time-mix) ----------
__global__ __launch_bounds__(256) void lnmix3_kernel(const float* __restrict__ x,
    const float* __restrict__ g, const float* __restrict__ b,
    const float* __restrict__ mk, const float* __restrict__ mv, const float* __restrict__ mr,
    u16* __restrict__ xk, u16* __restrict__ xv, u16* __restrict__ xr) {
  __shared__ float red[16];
  const int m = blockIdx.x, tid = threadIdx.x;
  const bool first = (m % T) == 0;
  f32x4 v = *(const f32x4*)&x[(size_t)m * D + tid * 4];
  f32x4 vp = {0.0f, 0.0f, 0.0f, 0.0f};
  if (!first) vp = *(const f32x4*)&x[(size_t)(m - 1) * D + tid * 4];
  float s  = v[0] + v[1] + v[2] + v[3];
  float s2 = v[0]*v[0] + v[1]*v[1] + v[2]*v[2] + v[3]*v[3];
  float p  = vp[0] + vp[1] + vp[2] + vp[3];
  float p2 = vp[0]*vp[0] + vp[1]*vp[1] + vp[2]*vp[2] + vp[3]*vp[3];
  #pragma unroll
  for (int o = 32; o > 0; o >>= 1) {
    s += __shfl_down(s, o); s2 += __shfl_down(s2, o);
    p += __shfl_down(p, o); p2 += __shfl_down(p2, o);
  }
  if ((tid & 63) == 0) {
    red[tid >> 6] = s; red[4 + (tid >> 6)] = s2;
    red[8 + (tid >> 6)] = p; red[12 + (tid >> 6)] = p2;
  }
  __syncthreads();
  s  = red[0] + red[1] + red[2] + red[3];
  s2 = red[4] + red[5] + red[6] + red[7];
  p  = red[8] + red[9] + red[10] + red[11];
  p2 = red[12] + red[13] + red[14] + red[15];
  const float mu  = s * (1.0f / D);
  const float rs  = rsqrtf(s2 * (1.0f / D) - mu * mu + 1e-5f);
  const float mup = p * (1.0f / D);
  const float rsp = rsqrtf(p2 * (1.0f / D) - mup * mup + 1e-5f);
  u16x4 ok, ov, orr;
  #pragma unroll
  for (int i = 0; i < 4; ++i) {
    const int d = tid * 4 + i;
    const float h  = (v[i] - mu) * rs * g[d] + b[d];
    const float hp = first ? 0.0f : (vp[i] - mup) * rsp * g[d] + b[d];
    float a;
    a = mk[d]; ok[i]  = f2bf(h * a + hp * (1.0f - a));
    a = mv[d]; ov[i]  = f2bf(h * a + hp * (1.0f - a));
    a = mr[d]; orr[i] = f2bf(h * a + hp * (1.0f - a));
  }
  const size_t base = (size_t)m * D + tid * 4;
  *(u16x4*)&xk[base] = ok;
  *(u16x4*)&xv[base] = ov;
  *(u16x4*)&xr[base] = orr;
}

// ---------- fused LayerNorm + token-shift mix, 2 outputs (channel-mix) ----------
__global__ __launch_bounds__(256) void lnmix2_kernel(const float* __restrict__ x,
    const float* __restrict__ g, const float* __restrict__ b,
    const float* __restrict__ mk, const float* __restrict__ mr,
    u16* __restrict__ xk, u16* __restrict__ xr) {
  __shared__ float red[16];
  const int m = blockIdx.x, tid = threadIdx.x;
  const bool first = (m % T) == 0;
  f32x4 v = *(const f32x4*)&x[(size_t)m * D + tid * 4];
  f32x4 vp = {0.0f, 0.0f, 0.0f, 0.0f};
  if (!first) vp = *(const f32x4*)&x[(size_t)(m - 1) * D + tid * 4];
  float s  = v[0] + v[1] + v[2] + v[3];
  float s2 = v[0]*v[0] + v[1]*v[1] + v[2]*v[2] + v[3]*v[3];
  float p  = vp[0] + vp[1] + vp[2] + vp[3];
  float p2 = vp[0]*vp[0] + vp[1]*vp[1] + vp[2]*vp[2] + vp[3]*vp[3];
  #pragma unroll
  for (int o = 32; o > 0; o >>= 1) {
    s += __shfl_down(s, o); s2 += __shfl_down(s2, o);
    p += __shfl_down(p, o); p2 += __shfl_down(p2, o);
  }
  if ((tid & 63) == 0) {
    red[tid >> 6] = s; red[4 + (tid >> 6)] = s2;
    red[8 + (tid >> 6)] = p; red[12 + (tid >> 6)] = p2;
  }
  __syncthreads();
  s  = red[0] + red[1] + red[2] + red[3];
  s2 = red[4] + red[5] + red[6] + red[7];
  p  = red[8] + red[9] + red[10] + red[11];
  p2 = red[12] + red[13] + red[14] + red[15];
  const float mu  = s * (1.0f / D);
  const float rs  = rsqrtf(s2 * (1.0f / D) - mu * mu + 1e-5f);
  const float mup = p * (1.0f / D);
  const float rsp = rsqrtf(p2 * (1.0f / D) - mup * mup + 1e-5f);
  u16x4 ok, orr;
  #pragma unroll
  for (int i = 0; i < 4; ++i) {
    const int d = tid * 4 + i;
    const float h  = (v[i] - mu) * rs * g[d] + b[d];
    const float hp = first ? 0.0f : (vp[i] - mup) * rsp * g[d] + b[d];
    float a;
    a = mk[d]; ok[i]  = f2bf(h * a + hp * (1.0f - a));
    a = mr[d]; orr[i] = f2bf(h * a + hp * (1.0f - a));
  }
  const size_t base = (size_t)m * D + tid * 4;
  *(u16x4*)&xk[base] = ok;
  *(u16x4*)&xr[base] = orr;
}

// ---------- weight transpose + f32->bf16: in[K,N] f32 -> out[N,K] bf16 ----------
__global__ __launch_bounds__(256) void transpose_bf16_kernel(const float* __restrict__ in,
                                                             u16* __restrict__ out,
                                                             int K_, int N_) {
  __shared__ u16 t[32][33];
  const int k0 = blockIdx.x * 32, n0 = blockIdx.y * 32;
  const int r = threadIdx.x >> 5, c = threadIdx.x & 31;   // 8 x 32
  #pragma unroll
  for (int p = 0; p < 4; ++p)
    t[r + p * 8][c] = f2bf(in[(size_t)(k0 + r + p * 8) * N_ + n0 + c]);
  __syncthreads();
  #pragma unroll
  for (int p = 0; p < 4; ++p)
    out[(size_t)(n0 + r + p * 8) * K_ + k0 + c] = t[c][r + p * 8];
}

// ---------- chunk-parallel WKV scan (K bf16) ----------
__global__ __launch_bounds__(256) void wkv_phase1(const u16* __restrict__ K_,
                                                  const u16* __restrict__ V_,
                                                  const float* __restrict__ td,
                                                  float* __restrict__ aggA,
                                                  float* __restrict__ aggB,
                                                  float* __restrict__ aggP) {
  const int gid = blockIdx.x * 256 + threadIdx.x;   // ((b*NCH + c)*D + d)
  const int d = gid & (D - 1);
  const int c = (gid >> 10) & (NCH - 1);
  const int b = gid >> 15;
  const float w = -expf(td[d]);
  float a = 0.0f, bb = 0.0f, p = -1e38f;
  size_t idx = ((size_t)b * T + (size_t)c * CL) * D + d;
  for (int t = 0; t < CL; ++t, idx += D) {
    const float kt = bf2f(K_[idx]);
    const float vt = bf2f(V_[idx]);
    const float wp = p + w;
    const float pn = fmaxf(wp, kt);
    const float e1 = expf(wp - pn), e2 = expf(kt - pn);
    a  = e1 * a  + e2 * vt;
    bb = e1 * bb + e2;
    p  = pn;
  }
  aggA[gid] = a; aggB[gid] = bb; aggP[gid] = p;
}

__global__ __launch_bounds__(256) void wkv_phase2(const float* __restrict__ td,
                                                  const float* __restrict__ aggA,
                                                  const float* __restrict__ aggB,
                                                  const float* __restrict__ aggP,
                                                  float* __restrict__ incA,
                                                  float* __restrict__ incB,
                                                  float* __restrict__ incP) {
  const int gid = blockIdx.x * 256 + threadIdx.x;   // b*D + d
  const int d = gid & (D - 1);
  const int b = gid >> 10;
  const float cw = -expf(td[d]) * (float)CL;
  float a = 0.0f, bb = 0.0f, p = -1e38f;
  for (int c = 0; c < NCH; ++c) {
    const int i = (b * NCH + c) * D + d;
    incA[i] = a; incB[i] = bb; incP[i] = p;
    const float pd = p + cw;           // decay state across this chunk
    const float pc = aggP[i];
    const float pn = fmaxf(pd, pc);
    const float e1 = expf(pd - pn), e2 = expf(pc - pn);
    a  = e1 * a  + e2 * aggA[i];
    bb = e1 * bb + e2 * aggB[i];
    p  = pn;
  }
}

__global__ __launch_bounds__(256) void wkv_phase3(const u16* __restrict__ K_,
                                                  const u16* __restrict__ V_,
                                                  const u16* __restrict__ R_,
                                                  const float* __restrict__ td,
                                                  const float* __restrict__ tf,
                                                  const float* __restrict__ incA,
                                                  const float* __restrict__ incB,
                                                  const float* __restrict__ incP,
                                                  u16* __restrict__ a2) {
  const int gid = blockIdx.x * 256 + threadIdx.x;
  const int d = gid & (D - 1);
  const int c = (gid >> 10) & (NCH - 1);
  const int b = gid >> 15;
  const float w = -expf(td[d]);
  const float u = tf[d];
  float aa = incA[gid], bb = incB[gid], pp = incP[gid];
  size_t idx = ((size_t)b * T + (size_t)c * CL) * D + d;
  for (int t = 0; t < CL; ++t, idx += D) {
    const float kt = bf2f(K_[idx]);
    const float vt = bf2f(V_[idx]);
    const float rt = bf2f(R_[idx]);
    const float ww = u + kt;
    const float p  = fmaxf(pp, ww);
    const float e1 = expf(pp - p), e2 = expf(ww - p);
    const float o  = (e1 * aa + e2 * vt) / (e1 * bb + e2);
    a2[idx] = f2bf(rt * o);
    const float ww2 = pp + w;
    const float p2  = fmaxf(ww2, kt);
    const float e1b = expf(ww2 - p2), e2b = expf(kt - p2);
    aa = e1b * aa + e2b * vt;
    bb = e1b * bb + e2b;
    pp = p2;
  }
}

// ---------- 256x256 bf16 MFMA GEMM — m201 8-phase skeleton (best measured) ----------
// 8 waves (2M x 4N), BK=64, 128KB LDS dbuf, 16x16x32 MFMA. Per phase:
//   {ds_read this phase's frags; stage gloads; [lgkmcnt(8) if 12 reads];
//    s_barrier; lgkmcnt(0); sched_barrier(0); setprio(1); 16 MFMA; setprio(0); s_barrier}
// vmcnt(6) once per K-tile at phase 3. Stage rows disjoint from unretired reads.
// EPI: 0 f32 | 1 sigmoid->bf16 | 2 auxf+C->f32 | 3 relu(C)^2->bf16 | 4 dst+=bf16(auxh)*C | 5 bf16
template <int EPI>
__global__ __launch_bounds__(512, 2) void gemm8(const u16* __restrict__ A,
                                                const u16* __restrict__ Bt,
                                                int N, int K,
                                                float* __restrict__ outf,
                                                u16* __restrict__ outh,
                                                const float* __restrict__ auxf,
                                                const u16* __restrict__ auxh,
                                                float* __restrict__ dst) {
  __shared__ u16 sm[65536];           // [0,32768): A bufs, [32768,65536): B bufs
  const int gx = gridDim.x, gy = gridDim.y;
  const int fid = blockIdx.y * gx + blockIdx.x;
  const int xcd = fid & 7, sl = fid >> 3;
  const int m0 = (xcd * (gx >> 3) + sl / gy) * 256;   // XCD-stripe mapping (gx%8==0)
  const int n0 = (sl % gy) * 256;

  const int tid = threadIdx.x;
  const int w = tid >> 6, l = tid & 63;
  const int wm = w >> 2, wn = w & 3;
  const int lr = l >> 3, ls = l & 7;
  const int NT = K >> 6;
  f32x4 acc[8][4] = {};

  const u16* gA = A + (size_t)(m0 + w * 8 + lr) * K + (ls ^ lr) * 8;
  const u16* gB = Bt + (size_t)(n0 + w * 8 + lr) * K + (ls ^ lr) * 8;

  auto stA = [&](int j, int r) {
    gload16(gA + ((size_t)r * 64) * K + (size_t)j * 64,
            &sm[(j & 1) * 16384 + (r * 64 + w * 8) * 64]);
  };
  auto stB = [&](int j, int r) {
    gload16(gB + ((size_t)r * 64) * K + (size_t)j * 64,
            &sm[32768 + (j & 1) * 16384 + (r * 64 + w * 8) * 64]);
  };

  u16x8 bF[4][2], aF[2][2];

  auto ldB8 = [&](const u16* sB) {
    #pragma unroll
    for (int ni = 0; ni < 4; ++ni)
      #pragma unroll
      for (int ks = 0; ks < 2; ++ks) {
        const int rb = wn * 64 + ni * 16 + (l & 15);
        const int rs = ks * 4 + (l >> 4);
        bF[ni][ks] = *(const u16x8*)&sB[rb * 64 + ((rs ^ (rb & 7)) * 8)];
      }
  };

#define LDA(q, sAp)                                                         \
  _Pragma("unroll") for (int mi = 0; mi < 2; ++mi)                          \
    _Pragma("unroll") for (int ks = 0; ks < 2; ++ks) {                      \
      const int ra = wm * 128 + (q) * 32 + mi * 16 + (l & 15);              \
      const int rs = ks * 4 + (l >> 4);                                     \
      aF[mi][ks] = *(const u16x8*)&sAp[ra * 64 + ((rs ^ (ra & 7)) * 8)];    \
    }

#define MFMA16(Q)                                                           \
  __builtin_amdgcn_s_setprio(1);                                            \
  _Pragma("unroll") for (int ks = 0; ks < 2; ++ks)                          \
    _Pragma("unroll") for (int mi = 0; mi < 2; ++mi)                        \
      _Pragma("unroll") for (int ni = 0; ni < 4; ++ni)                      \
        acc[(Q) * 2 + mi][ni] = __builtin_amdgcn_mfma_f32_16x16x32_bf16(    \
            __builtin_bit_cast(bf16x8, aF[mi][ks]),                         \
            __builtin_bit_cast(bf16x8, bF[ni][ks]),                         \
            acc[(Q) * 2 + mi][ni], 0, 0, 0);                                \
  __builtin_amdgcn_s_setprio(0);

#define LGKM0_FENCE                                                         \
  asm volatile("s_waitcnt lgkmcnt(0)" ::: "memory");                        \
  __builtin_amdgcn_sched_barrier(0);

  // prologue: tile0 fully (8 rounds), then tile1 fully (8 rounds)
  stB(0, 0); stB(0, 1); stB(0, 2); stB(0, 3);
  stA(0, 0); stA(0, 1); stA(0, 2); stA(0, 3);
  if (1 < NT) {
    stB(1, 0); stB(1, 1); stB(1, 2); stB(1, 3);
    stA(1, 0); stA(1, 1); stA(1, 2); stA(1, 3);
    asm volatile("s_waitcnt vmcnt(8)" ::: "memory");   // tile0 resident; tile1 in flight
  } else {
    asm volatile("s_waitcnt vmcnt(0)" ::: "memory");
  }
  __builtin_amdgcn_s_barrier();

  for (int k = 0; k < NT; ++k) {
    const u16* sA = &sm[(k & 1) * 16384];
    const u16* sB = &sm[32768 + (k & 1) * 16384];
    const bool s2 = (k + 2 < NT);
    // ---- phase 0: bF(8) + aF0(4) reads ----
    ldB8(sB);
    LDA(0, sA);
    asm volatile("s_waitcnt lgkmcnt(8)" ::: "memory");   // stagger (12-read phase)
    __builtin_amdgcn_s_barrier();
    LGKM0_FENCE
    MFMA16(0);
    __builtin_amdgcn_s_barrier();
    // ---- phase 1 ----
    LDA(1, sA);
    if (s2) { stB(k + 2, 0); stB(k + 2, 1); }
    __builtin_amdgcn_s_barrier();
    LGKM0_FENCE
    MFMA16(1);
    __builtin_amdgcn_s_barrier();
    // ---- phase 2 ----
    LDA(2, sA);
    if (s2) { stB(k + 2, 2); stB(k + 2, 3); stA(k + 2, 0); stA(k + 2, 2); }
    __builtin_amdgcn_s_barrier();
    LGKM0_FENCE
    MFMA16(2);
    __builtin_amdgcn_s_barrier();
    // ---- phase 3: stage A r1,r3 after drain (aF3 retired); counted vmcnt ----
    LDA(3, sA);
    __builtin_amdgcn_s_barrier();
    LGKM0_FENCE
    if (s2) {
      stA(k + 2, 1); stA(k + 2, 3);
      asm volatile("s_waitcnt vmcnt(6)" ::: "memory");   // all of tile k+1 retired
    } else if (k + 1 < NT) {
      asm volatile("s_waitcnt vmcnt(0)" ::: "memory");
    }
    MFMA16(3);
    __builtin_amdgcn_s_barrier();
  }
#undef LDA
#undef MFMA16
#undef LGKM0_FENCE

  const int cl = l & 15, rh = l >> 4;
  #pragma unroll
  for (int mi = 0; mi < 8; ++mi) {
    #pragma unroll
    for (int ni = 0; ni < 4; ++ni) {
      const int gn = n0 + wn * 64 + ni * 16 + cl;
      #pragma unroll
      for (int j = 0; j < 4; ++j) {
        const int gm = m0 + wm * 128 + mi * 16 + rh * 4 + j;
        const float c = acc[mi][ni][j];
        const size_t o = (size_t)gm * N + gn;
        if (EPI == 0) outf[o] = c;
        else if (EPI == 1) outh[o] = f2bf(1.0f / (1.0f + expf(-c)));
        else if (EPI == 2) outf[o] = auxf[o] + c;
        else if (EPI == 3) { const float t = c > 0.0f ? c : 0.0f; outh[o] = f2bf(t * t); }
        else if (EPI == 4) dst[o] += bf2f(auxh[o]) * c;
        else if (EPI == 5) outh[o] = f2bf(c);
      }
    }
  }
}

extern "C" void kernel_launch(void* const* d_in, const int* in_sizes, int n_in,
                              void* d_out, int out_size, void* d_ws, size_t ws_size,
                              hipStream_t stream) {
  (void)in_sizes; (void)n_in; (void)out_size;
  const float* x      = (const float*)d_in[0];
  const float* ln1_g  = (const float*)d_in[1];
  const float* ln1_b  = (const float*)d_in[2];
  const float* ln2_g  = (const float*)d_in[3];
  const float* ln2_b  = (const float*)d_in[4];
  const float* tm_k   = (const float*)d_in[5];
  const float* tm_v   = (const float*)d_in[6];
  const float* tm_r   = (const float*)d_in[7];
  const float* tdec   = (const float*)d_in[8];
  const float* tfir   = (const float*)d_in[9];
  const float* wk     = (const float*)d_in[10];
  const float* wv     = (const float*)d_in[11];
  const float* wr     = (const float*)d_in[12];
  const float* wo     = (const float*)d_in[13];
  const float* cm_k   = (const float*)d_in[14];
  const float* cm_r   = (const float*)d_in[15];
  const float* cwk    = (const float*)d_in[16];
  const float* cwv    = (const float*)d_in[17];
  const float* cwr    = (const float*)d_in[18];
  float* out = (float*)d_out;

  const size_t MB = 1024 * 1024;
  if (ws_size < 218 * MB) return;   // diagnostic: leaves d_out poisoned

  char* w = (char*)d_ws;
  // region map (MB):
  u16*   h    = (u16*)(w);             // [0,32):  R -> rr
  u16*   b32  = (u16*)(w + 32 * MB);   // [32,64): xk -> V -> xck
  u16*   b64  = (u16*)(w + 64 * MB);   // [64,96): xv -> a2 -> xcr -> (KK head)
  u16*   b96  = (u16*)(w + 96 * MB);   // [96,128): xr -> scan scratch -> (KK)
  u16*   Kb   = (u16*)(w + 128 * MB);  // [128,160): K bf16 -> (KK tail)
  u16*   KK   = (u16*)(w + 64 * MB);   // [64,192): full M x FF bf16 (after deps dead)
  u16*   wkT  = (u16*)(w + 192 * MB);  // 2 MB each
  u16*   wvT  = (u16*)(w + 194 * MB);
  u16*   wrT  = (u16*)(w + 196 * MB);
  u16*   woT  = (u16*)(w + 198 * MB);
  u16*   cwkT = (u16*)(w + 200 * MB);  // 8 MB [FF,D]
  u16*   cwvT = (u16*)(w + 208 * MB);  // 8 MB [D,FF]
  u16*   cwrT = (u16*)(w + 216 * MB);  // 2 MB -> total 218 MB
  // scan scratch inside [96,128) (xr dead after R GEMM; KK written after scan):
  float* aggA = (float*)(w + 96 * MB);
  float* aggB = (float*)(w + 97 * MB);
  float* aggP = (float*)(w + 98 * MB);
  float* incA = (float*)(w + 99 * MB);
  float* incB = (float*)(w + 100 * MB);
  float* incP = (float*)(w + 101 * MB);

  // ---- weights: transpose + cast to bf16 ----
  transpose_bf16_kernel<<<dim3(D / 32, D / 32), 256, 0, stream>>>(wk, wkT, D, D);
  transpose_bf16_kernel<<<dim3(D / 32, D / 32), 256, 0, stream>>>(wv, wvT, D, D);
  transpose_bf16_kernel<<<dim3(D / 32, D / 32), 256, 0, stream>>>(wr, wrT, D, D);
  transpose_bf16_kernel<<<dim3(D / 32, D / 32), 256, 0, stream>>>(wo, woT, D, D);
  transpose_bf16_kernel<<<dim3(D / 32, FF / 32), 256, 0, stream>>>(cwk, cwkT, D, FF);
  transpose_bf16_kernel<<<dim3(FF / 32, D / 32), 256, 0, stream>>>(cwv, cwvT, FF, D);
  transpose_bf16_kernel<<<dim3(D / 32, D / 32), 256, 0, stream>>>(cwr, cwrT, D, D);

  // ---- time mixing (fused LN+mix) ----
  lnmix3_kernel<<<M, 256, 0, stream>>>(x, ln1_g, ln1_b, tm_k, tm_v, tm_r, b32, b64, b96);

  dim3 gD(M / 256, D / 256);      // (64, 4)
  // K = xk @ wk (bf16)
  gemm8<5><<<gD, 512, 0, stream>>>(b32, wkT, D, D, nullptr, Kb, nullptr, nullptr, nullptr);
  // V = xv @ wv (bf16) -> b32 (xk dead)
  gemm8<5><<<gD, 512, 0, stream>>>(b64, wvT, D, D, nullptr, b32, nullptr, nullptr, nullptr);
  // R = sigmoid(xr @ wr) (bf16) -> h
  gemm8<1><<<gD, 512, 0, stream>>>(b96, wrT, D, D, nullptr, h, nullptr, nullptr, nullptr);

  // chunk-parallel scan: a2 = bf16(r * wkv) -> b64 (xv dead)
  wkv_phase1<<<(NB * NCH * D) / 256, 256, 0, stream>>>(Kb, b32, tdec, aggA, aggB, aggP);
  wkv_phase2<<<(NB * D) / 256, 256, 0, stream>>>(tdec, aggA, aggB, aggP, incA, incB, incP);
  wkv_phase3<<<(NB * NCH * D) / 256, 256, 0, stream>>>(Kb, b32, h, tdec, tfir,
                                                       incA, incB, incP, b64);

  // out = x + a2 @ wo
  gemm8<2><<<gD, 512, 0, stream>>>(b64, woT, D, D, out, nullptr, x, nullptr, nullptr);

  // ---- channel mixing (fused LN+mix) ----
  lnmix2_kernel<<<M, 256, 0, stream>>>(out, ln2_g, ln2_b, cm_k, cm_r, b32, b64); // xck, xcr

  // rr = sigmoid(xcr @ cwr) (bf16) -> h (R dead)
  gemm8<1><<<gD, 512, 0, stream>>>(b64, cwrT, D, D, nullptr, h, nullptr, nullptr, nullptr);

  // KK = relu(xck @ cwk)^2 (bf16) -> [64,192) (xcr/scratch/Kb all dead)
  dim3 gF(M / 256, FF / 256);     // (64, 16)
  gemm8<3><<<gF, 512, 0, stream>>>(b32, cwkT, FF, D, nullptr, KK, nullptr, nullptr, nullptr);

  // out += rr * (KK @ cwv)
  dim3 gO(M / 256, D / 256);      // (64, 4), K = FF
  gemm8<4><<<gO, 512, 0, stream>>>(KK, cwvT, D, FF, nullptr, nullptr, nullptr, h, out);
}

// Round 15
// 692.620 us; speedup vs baseline: 1.0741x; 1.0241x over previous
//
#include <hip/hip_runtime.h>

typedef unsigned short u16;
typedef float f32x4 __attribute__((ext_vector_type(4)));
typedef __bf16 bf16x8 __attribute__((ext_vector_type(8)));
typedef u16 u16x8 __attribute__((ext_vector_type(8)));
typedef u16 u16x4 __attribute__((ext_vector_type(4)));

static constexpr int D  = 1024;
static constexpr int T  = 2048;
static constexpr int NB = 8;            // batch
static constexpr int M  = NB * T;       // 16384 rows
static constexpr int FF = 4096;
static constexpr int NCH = 32;          // scan chunks per sequence
static constexpr int CL  = T / NCH;     // 64 steps per chunk

__device__ __forceinline__ u16 f2bf(float f) {
  unsigned u = __builtin_bit_cast(unsigned, f);
  return (u16)((u + 0x7fffu + ((u >> 16) & 1u)) >> 16);   // RNE
}
__device__ __forceinline__ float bf2f(u16 s) {
  return __builtin_bit_cast(float, (unsigned)s << 16);
}

// async global->LDS 16B: LDS dest is wave-uniform base + lane*16 (m104);
// swizzling is done by pre-swizzling the per-lane GLOBAL address (m173).
__device__ __forceinline__ void gload16(const u16* g, u16* l) {
  __builtin_amdgcn_global_load_lds(
      (const __attribute__((address_space(1))) void*)g,
      (__attribute__((address_space(3))) void*)l, 16, 0, 0);
}

// ---------- mega-prologue: 7 weight transposes + lnmix3, one launch ----------
// blocks [0,13312): transpose+cast regions; [13312, 13312+M): lnmix3 rows.
// All pieces read only kernel inputs and write disjoint ws regions.
__global__ __launch_bounds__(256) void prologue_kernel(
    const float* __restrict__ wk, const float* __restrict__ wv,
    const float* __restrict__ wr, const float* __restrict__ wo,
    const float* __restrict__ cwk, const float* __restrict__ cwv,
    const float* __restrict__ cwr,
    u16* __restrict__ wkT, u16* __restrict__ wvT, u16* __restrict__ wrT,
    u16* __restrict__ woT, u16* __restrict__ cwkT, u16* __restrict__ cwvT,
    u16* __restrict__ cwrT,
    const float* __restrict__ x, const float* __restrict__ g,
    const float* __restrict__ b,
    const float* __restrict__ mk, const float* __restrict__ mv,
    const float* __restrict__ mr,
    u16* __restrict__ xk, u16* __restrict__ xv, u16* __restrict__ xr) {
  __shared__ u16 t[32][33];
  __shared__ float red[16];
  const int bid = blockIdx.x;
  const int tid = threadIdx.x;

  if (bid < 13312) {
    // ---- transpose region ----
    const float* in; u16* out; int K_, N_, lid;
    if (bid < 1024)       { in = wk;  out = wkT;  K_ = D;  N_ = D;  lid = bid; }
    else if (bid < 2048)  { in = wv;  out = wvT;  K_ = D;  N_ = D;  lid = bid - 1024; }
    else if (bid < 3072)  { in = wr;  out = wrT;  K_ = D;  N_ = D;  lid = bid - 2048; }
    else if (bid < 4096)  { in = wo;  out = woT;  K_ = D;  N_ = D;  lid = bid - 3072; }
    else if (bid < 8192)  { in = cwk; out = cwkT; K_ = D;  N_ = FF; lid = bid - 4096; }
    else if (bid < 12288) { in = cwv; out = cwvT; K_ = FF; N_ = D;  lid = bid - 8192; }
    else                  { in = cwr; out = cwrT; K_ = D;  N_ = D;  lid = bid - 12288; }
    const int nbx = K_ / 32;
    const int k0 = (lid % nbx) * 32, n0 = (lid / nbx) * 32;
    const int r = tid >> 5, c = tid & 31;   // 8 x 32
    #pragma unroll
    for (int p = 0; p < 4; ++p)
      t[r + p * 8][c] = f2bf(in[(size_t)(k0 + r + p * 8) * N_ + n0 + c]);
    __syncthreads();
    #pragma unroll
    for (int p = 0; p < 4; ++p)
      out[(size_t)(n0 + r + p * 8) * K_ + k0 + c] = t[c][r + p * 8];
    return;
  }

  // ---- lnmix3 region ----
  const int m = bid - 13312;
  const bool first = (m % T) == 0;
  f32x4 v = *(const f32x4*)&x[(size_t)m * D + tid * 4];
  f32x4 vp = {0.0f, 0.0f, 0.0f, 0.0f};
  if (!first) vp = *(const f32x4*)&x[(size_t)(m - 1) * D + tid * 4];
  float s  = v[0] + v[1] + v[2] + v[3];
  float s2 = v[0]*v[0] + v[1]*v[1] + v[2]*v[2] + v[3]*v[3];
  float p  = vp[0] + vp[1] + vp[2] + vp[3];
  float p2 = vp[0]*vp[0] + vp[1]*vp[1] + vp[2]*vp[2] + vp[3]*vp[3];
  #pragma unroll
  for (int o = 32; o > 0; o >>= 1) {
    s += __shfl_down(s, o); s2 += __shfl_down(s2, o);
    p += __shfl_down(p, o); p2 += __shfl_down(p2, o);
  }
  if ((tid & 63) == 0) {
    red[tid >> 6] = s; red[4 + (tid >> 6)] = s2;
    red[8 + (tid >> 6)] = p; red[12 + (tid >> 6)] = p2;
  }
  __syncthreads();
  s  = red[0] + red[1] + red[2] + red[3];
  s2 = red[4] + red[5] + red[6] + red[7];
  p  = red[8] + red[9] + red[10] + red[11];
  p2 = red[12] + red[13] + red[14] + red[15];
  const float mu  = s * (1.0f / D);
  const float rs  = rsqrtf(s2 * (1.0f / D) - mu * mu + 1e-5f);
  const float mup = p * (1.0f / D);
  const float rsp = rsqrtf(p2 * (1.0f / D) - mup * mup + 1e-5f);
  u16x4 ok, ov, orr;
  #pragma unroll
  for (int i = 0; i < 4; ++i) {
    const int d = tid * 4 + i;
    const float h  = (v[i] - mu) * rs * g[d] + b[d];
    const float hp = first ? 0.0f : (vp[i] - mup) * rsp * g[d] + b[d];
    float a;
    a = mk[d]; ok[i]  = f2bf(h * a + hp * (1.0f - a));
    a = mv[d]; ov[i]  = f2bf(h * a + hp * (1.0f - a));
    a = mr[d]; orr[i] = f2bf(h * a + hp * (1.0f - a));
  }
  const size_t base = (size_t)m * D + tid * 4;
  *(u16x4*)&xk[base] = ok;
  *(u16x4*)&xv[base] = ov;
  *(u16x4*)&xr[base] = orr;
}

// ---------- fused LayerNorm + token-shift mix, 2 outputs (channel-mix) ----------
__global__ __launch_bounds__(256) void lnmix2_kernel(const float* __restrict__ x,
    const float* __restrict__ g, const float* __restrict__ b,
    const float* __restrict__ mk, const float* __restrict__ mr,
    u16* __restrict__ xk, u16* __restrict__ xr) {
  __shared__ float red[16];
  const int m = blockIdx.x, tid = threadIdx.x;
  const bool first = (m % T) == 0;
  f32x4 v = *(const f32x4*)&x[(size_t)m * D + tid * 4];
  f32x4 vp = {0.0f, 0.0f, 0.0f, 0.0f};
  if (!first) vp = *(const f32x4*)&x[(size_t)(m - 1) * D + tid * 4];
  float s  = v[0] + v[1] + v[2] + v[3];
  float s2 = v[0]*v[0] + v[1]*v[1] + v[2]*v[2] + v[3]*v[3];
  float p  = vp[0] + vp[1] + vp[2] + vp[3];
  float p2 = vp[0]*vp[0] + vp[1]*vp[1] + vp[2]*vp[2] + vp[3]*vp[3];
  #pragma unroll
  for (int o = 32; o > 0; o >>= 1) {
    s += __shfl_down(s, o); s2 += __shfl_down(s2, o);
    p += __shfl_down(p, o); p2 += __shfl_down(p2, o);
  }
  if ((tid & 63) == 0) {
    red[tid >> 6] = s; red[4 + (tid >> 6)] = s2;
    red[8 + (tid >> 6)] = p; red[12 + (tid >> 6)] = p2;
  }
  __syncthreads();
  s  = red[0] + red[1] + red[2] + red[3];
  s2 = red[4] + red[5] + red[6] + red[7];
  p  = red[8] + red[9] + red[10] + red[11];
  p2 = red[12] + red[13] + red[14] + red[15];
  const float mu  = s * (1.0f / D);
  const float rs  = rsqrtf(s2 * (1.0f / D) - mu * mu + 1e-5f);
  const float mup = p * (1.0f / D);
  const float rsp = rsqrtf(p2 * (1.0f / D) - mup * mup + 1e-5f);
  u16x4 ok, orr;
  #pragma unroll
  for (int i = 0; i < 4; ++i) {
    const int d = tid * 4 + i;
    const float h  = (v[i] - mu) * rs * g[d] + b[d];
    const float hp = first ? 0.0f : (vp[i] - mup) * rsp * g[d] + b[d];
    float a;
    a = mk[d]; ok[i]  = f2bf(h * a + hp * (1.0f - a));
    a = mr[d]; orr[i] = f2bf(h * a + hp * (1.0f - a));
  }
  const size_t base = (size_t)m * D + tid * 4;
  *(u16x4*)&xk[base] = ok;
  *(u16x4*)&xr[base] = orr;
}

// ---------- chunk-parallel WKV scan (K bf16) ----------
__global__ __launch_bounds__(256) void wkv_phase1(const u16* __restrict__ K_,
                                                  const u16* __restrict__ V_,
                                                  const float* __restrict__ td,
                                                  float* __restrict__ aggA,
                                                  float* __restrict__ aggB,
                                                  float* __restrict__ aggP) {
  const int gid = blockIdx.x * 256 + threadIdx.x;   // ((b*NCH + c)*D + d)
  const int d = gid & (D - 1);
  const int c = (gid >> 10) & (NCH - 1);
  const int b = gid >> 15;
  const float w = -expf(td[d]);
  float a = 0.0f, bb = 0.0f, p = -1e38f;
  size_t idx = ((size_t)b * T + (size_t)c * CL) * D + d;
  for (int t = 0; t < CL; ++t, idx += D) {
    const float kt = bf2f(K_[idx]);
    const float vt = bf2f(V_[idx]);
    const float wp = p + w;
    const float pn = fmaxf(wp, kt);
    const float e1 = expf(wp - pn), e2 = expf(kt - pn);
    a  = e1 * a  + e2 * vt;
    bb = e1 * bb + e2;
    p  = pn;
  }
  aggA[gid] = a; aggB[gid] = bb; aggP[gid] = p;
}

__global__ __launch_bounds__(256) void wkv_phase2(const float* __restrict__ td,
                                                  const float* __restrict__ aggA,
                                                  const float* __restrict__ aggB,
                                                  const float* __restrict__ aggP,
                                                  float* __restrict__ incA,
                                                  float* __restrict__ incB,
                                                  float* __restrict__ incP) {
  const int gid = blockIdx.x * 256 + threadIdx.x;   // b*D + d
  const int d = gid & (D - 1);
  const int b = gid >> 10;
  const float cw = -expf(td[d]) * (float)CL;
  float a = 0.0f, bb = 0.0f, p = -1e38f;
  for (int c = 0; c < NCH; ++c) {
    const int i = (b * NCH + c) * D + d;
    incA[i] = a; incB[i] = bb; incP[i] = p;
    const float pd = p + cw;           // decay state across this chunk
    const float pc = aggP[i];
    const float pn = fmaxf(pd, pc);
    const float e1 = expf(pd - pn), e2 = expf(pc - pn);
    a  = e1 * a  + e2 * aggA[i];
    bb = e1 * bb + e2 * aggB[i];
    p  = pn;
  }
}

__global__ __launch_bounds__(256) void wkv_phase3(const u16* __restrict__ K_,
                                                  const u16* __restrict__ V_,
                                                  const u16* __restrict__ R_,
                                                  const float* __restrict__ td,
                                                  const float* __restrict__ tf,
                                                  const float* __restrict__ incA,
                                                  const float* __restrict__ incB,
                                                  const float* __restrict__ incP,
                                                  u16* __restrict__ a2) {
  const int gid = blockIdx.x * 256 + threadIdx.x;
  const int d = gid & (D - 1);
  const int c = (gid >> 10) & (NCH - 1);
  const int b = gid >> 15;
  const float w = -expf(td[d]);
  const float u = tf[d];
  float aa = incA[gid], bb = incB[gid], pp = incP[gid];
  size_t idx = ((size_t)b * T + (size_t)c * CL) * D + d;
  for (int t = 0; t < CL; ++t, idx += D) {
    const float kt = bf2f(K_[idx]);
    const float vt = bf2f(V_[idx]);
    const float rt = bf2f(R_[idx]);
    const float ww = u + kt;
    const float p  = fmaxf(pp, ww);
    const float e1 = expf(pp - p), e2 = expf(ww - p);
    const float o  = (e1 * aa + e2 * vt) / (e1 * bb + e2);
    a2[idx] = f2bf(rt * o);
    const float ww2 = pp + w;
    const float p2  = fmaxf(ww2, kt);
    const float e1b = expf(ww2 - p2), e2b = expf(kt - p2);
    aa = e1b * aa + e2b * vt;
    bb = e1b * bb + e2b;
    pp = p2;
  }
}

// ---------- 256x256 bf16 MFMA GEMM core — m201 8-phase skeleton (best measured) ----------
// 8 waves (2M x 4N), BK=64, 128KB LDS dbuf (passed in), 16x16x32 MFMA. Per phase:
//   {ds_read this phase's frags; stage gloads; [lgkmcnt(8) if 12 reads];
//    s_barrier; lgkmcnt(0); sched_barrier(0); setprio(1); 16 MFMA; setprio(0); s_barrier}
// vmcnt(6) once per K-tile at phase 3. Stage rows disjoint from unretired reads.
// EPI: 0 f32 | 1 sigmoid->bf16 | 2 auxf+C->f32 | 3 relu(C)^2->bf16 | 4 dst+=bf16(auxh)*C | 5 bf16
template <int EPI>
__device__ __forceinline__ void gemm_core(u16* sm,
                                          const u16* __restrict__ A,
                                          const u16* __restrict__ Bt,
                                          int N, int K,
                                          float* __restrict__ outf,
                                          u16* __restrict__ outh,
                                          const float* __restrict__ auxf,
                                          const u16* __restrict__ auxh,
                                          float* __restrict__ dst) {
  const int gx = gridDim.x, gy = gridDim.y;
  const int fid = blockIdx.y * gx + blockIdx.x;
  const int xcd = fid & 7, sl = fid >> 3;
  const int m0 = (xcd * (gx >> 3) + sl / gy) * 256;   // XCD-stripe mapping (gx%8==0)
  const int n0 = (sl % gy) * 256;

  const int tid = threadIdx.x;
  const int w = tid >> 6, l = tid & 63;
  const int wm = w >> 2, wn = w & 3;
  const int lr = l >> 3, ls = l & 7;
  const int NT = K >> 6;
  f32x4 acc[8][4] = {};

  const u16* gA = A + (size_t)(m0 + w * 8 + lr) * K + (ls ^ lr) * 8;
  const u16* gB = Bt + (size_t)(n0 + w * 8 + lr) * K + (ls ^ lr) * 8;

  auto stA = [&](int j, int r) {
    gload16(gA + ((size_t)r * 64) * K + (size_t)j * 64,
            &sm[(j & 1) * 16384 + (r * 64 + w * 8) * 64]);
  };
  auto stB = [&](int j, int r) {
    gload16(gB + ((size_t)r * 64) * K + (size_t)j * 64,
            &sm[32768 + (j & 1) * 16384 + (r * 64 + w * 8) * 64]);
  };

  u16x8 bF[4][2], aF[2][2];

  auto ldB8 = [&](const u16* sB) {
    #pragma unroll
    for (int ni = 0; ni < 4; ++ni)
      #pragma unroll
      for (int ks = 0; ks < 2; ++ks) {
        const int rb = wn * 64 + ni * 16 + (l & 15);
        const int rs = ks * 4 + (l >> 4);
        bF[ni][ks] = *(const u16x8*)&sB[rb * 64 + ((rs ^ (rb & 7)) * 8)];
      }
  };

#define LDA(q, sAp)                                                         \
  _Pragma("unroll") for (int mi = 0; mi < 2; ++mi)                          \
    _Pragma("unroll") for (int ks = 0; ks < 2; ++ks) {                      \
      const int ra = wm * 128 + (q) * 32 + mi * 16 + (l & 15);              \
      const int rs = ks * 4 + (l >> 4);                                     \
      aF[mi][ks] = *(const u16x8*)&sAp[ra * 64 + ((rs ^ (ra & 7)) * 8)];    \
    }

#define MFMA16(Q)                                                           \
  __builtin_amdgcn_s_setprio(1);                                            \
  _Pragma("unroll") for (int ks = 0; ks < 2; ++ks)                          \
    _Pragma("unroll") for (int mi = 0; mi < 2; ++mi)                        \
      _Pragma("unroll") for (int ni = 0; ni < 4; ++ni)                      \
        acc[(Q) * 2 + mi][ni] = __builtin_amdgcn_mfma_f32_16x16x32_bf16(    \
            __builtin_bit_cast(bf16x8, aF[mi][ks]),                         \
            __builtin_bit_cast(bf16x8, bF[ni][ks]),                         \
            acc[(Q) * 2 + mi][ni], 0, 0, 0);                                \
  __builtin_amdgcn_s_setprio(0);

#define LGKM0_FENCE                                                         \
  asm volatile("s_waitcnt lgkmcnt(0)" ::: "memory");                        \
  __builtin_amdgcn_sched_barrier(0);

  // prologue: tile0 fully (8 rounds), then tile1 fully (8 rounds)
  stB(0, 0); stB(0, 1); stB(0, 2); stB(0, 3);
  stA(0, 0); stA(0, 1); stA(0, 2); stA(0, 3);
  if (1 < NT) {
    stB(1, 0); stB(1, 1); stB(1, 2); stB(1, 3);
    stA(1, 0); stA(1, 1); stA(1, 2); stA(1, 3);
    asm volatile("s_waitcnt vmcnt(8)" ::: "memory");   // tile0 resident; tile1 in flight
  } else {
    asm volatile("s_waitcnt vmcnt(0)" ::: "memory");
  }
  __builtin_amdgcn_s_barrier();

  for (int k = 0; k < NT; ++k) {
    const u16* sA = &sm[(k & 1) * 16384];
    const u16* sB = &sm[32768 + (k & 1) * 16384];
    const bool s2 = (k + 2 < NT);
    // ---- phase 0: bF(8) + aF0(4) reads ----
    ldB8(sB);
    LDA(0, sA);
    asm volatile("s_waitcnt lgkmcnt(8)" ::: "memory");   // stagger (12-read phase)
    __builtin_amdgcn_s_barrier();
    LGKM0_FENCE
    MFMA16(0);
    __builtin_amdgcn_s_barrier();
    // ---- phase 1 ----
    LDA(1, sA);
    if (s2) { stB(k + 2, 0); stB(k + 2, 1); }
    __builtin_amdgcn_s_barrier();
    LGKM0_FENCE
    MFMA16(1);
    __builtin_amdgcn_s_barrier();
    // ---- phase 2 ----
    LDA(2, sA);
    if (s2) { stB(k + 2, 2); stB(k + 2, 3); stA(k + 2, 0); stA(k + 2, 2); }
    __builtin_amdgcn_s_barrier();
    LGKM0_FENCE
    MFMA16(2);
    __builtin_amdgcn_s_barrier();
    // ---- phase 3: stage A r1,r3 after drain (aF3 retired); counted vmcnt ----
    LDA(3, sA);
    __builtin_amdgcn_s_barrier();
    LGKM0_FENCE
    if (s2) {
      stA(k + 2, 1); stA(k + 2, 3);
      asm volatile("s_waitcnt vmcnt(6)" ::: "memory");   // all of tile k+1 retired
    } else if (k + 1 < NT) {
      asm volatile("s_waitcnt vmcnt(0)" ::: "memory");
    }
    MFMA16(3);
    __builtin_amdgcn_s_barrier();
  }
#undef LDA
#undef MFMA16
#undef LGKM0_FENCE

  const int cl = l & 15, rh = l >> 4;
  #pragma unroll
  for (int mi = 0; mi < 8; ++mi) {
    #pragma unroll
    for (int ni = 0; ni < 4; ++ni) {
      const int gn = n0 + wn * 64 + ni * 16 + cl;
      #pragma unroll
      for (int j = 0; j < 4; ++j) {
        const int gm = m0 + wm * 128 + mi * 16 + rh * 4 + j;
        const float c = acc[mi][ni][j];
        const size_t o = (size_t)gm * N + gn;
        if (EPI == 0) outf[o] = c;
        else if (EPI == 1) outh[o] = f2bf(1.0f / (1.0f + expf(-c)));
        else if (EPI == 2) outf[o] = auxf[o] + c;
        else if (EPI == 3) { const float t = c > 0.0f ? c : 0.0f; outh[o] = f2bf(t * t); }
        else if (EPI == 4) dst[o] += bf2f(auxh[o]) * c;
        else if (EPI == 5) outh[o] = f2bf(c);
      }
    }
  }
}

template <int EPI>
__global__ __launch_bounds__(512, 2) void gemm8(const u16* __restrict__ A,
                                                const u16* __restrict__ Bt,
                                                int N, int K,
                                                float* __restrict__ outf,
                                                u16* __restrict__ outh,
                                                const float* __restrict__ auxf,
                                                const u16* __restrict__ auxh,
                                                float* __restrict__ dst) {
  __shared__ u16 sm[65536];
  gemm_core<EPI>(sm, A, Bt, N, K, outf, outh, auxf, auxh, dst);
}

// ---------- fused K/V/R GEMM: blockIdx.z selects operand set (independent ops) ----------
__global__ __launch_bounds__(512, 2) void gemm_kvr(const u16* __restrict__ xk,
                                                   const u16* __restrict__ wkT,
                                                   u16* __restrict__ Kb,
                                                   const u16* __restrict__ xv,
                                                   const u16* __restrict__ wvT,
                                                   u16* __restrict__ Vb,
                                                   const u16* __restrict__ xr,
                                                   const u16* __restrict__ wrT,
                                                   u16* __restrict__ Rb) {
  __shared__ u16 sm[65536];
  if (blockIdx.z == 0)
    gemm_core<5>(sm, xk, wkT, D, D, nullptr, Kb, nullptr, nullptr, nullptr);
  else if (blockIdx.z == 1)
    gemm_core<5>(sm, xv, wvT, D, D, nullptr, Vb, nullptr, nullptr, nullptr);
  else
    gemm_core<1>(sm, xr, wrT, D, D, nullptr, Rb, nullptr, nullptr, nullptr);
}

extern "C" void kernel_launch(void* const* d_in, const int* in_sizes, int n_in,
                              void* d_out, int out_size, void* d_ws, size_t ws_size,
                              hipStream_t stream) {
  (void)in_sizes; (void)n_in; (void)out_size;
  const float* x      = (const float*)d_in[0];
  const float* ln1_g  = (const float*)d_in[1];
  const float* ln1_b  = (const float*)d_in[2];
  const float* ln2_g  = (const float*)d_in[3];
  const float* ln2_b  = (const float*)d_in[4];
  const float* tm_k   = (const float*)d_in[5];
  const float* tm_v   = (const float*)d_in[6];
  const float* tm_r   = (const float*)d_in[7];
  const float* tdec   = (const float*)d_in[8];
  const float* tfir   = (const float*)d_in[9];
  const float* wk     = (const float*)d_in[10];
  const float* wv     = (const float*)d_in[11];
  const float* wr     = (const float*)d_in[12];
  const float* wo     = (const float*)d_in[13];
  const float* cm_k   = (const float*)d_in[14];
  const float* cm_r   = (const float*)d_in[15];
  const float* cwk    = (const float*)d_in[16];
  const float* cwv    = (const float*)d_in[17];
  const float* cwr    = (const float*)d_in[18];
  float* out = (float*)d_out;

  const size_t MB = 1024 * 1024;
  if (ws_size < 218 * MB) return;   // diagnostic: leaves d_out poisoned

  char* w = (char*)d_ws;
  // region map (MB):
  u16*   h    = (u16*)(w);             // [0,32):  R -> rr
  u16*   b32  = (u16*)(w + 32 * MB);   // [32,64): xk -> xck
  u16*   b64  = (u16*)(w + 64 * MB);   // [64,96): xv -> a2 -> xcr -> (KK head)
  u16*   b96  = (u16*)(w + 96 * MB);   // [96,128): xr -> scan scratch -> (KK)
  u16*   Kb   = (u16*)(w + 128 * MB);  // [128,160): K bf16 -> (KK)
  u16*   Vb   = (u16*)(w + 160 * MB);  // [160,192): V bf16 -> (KK tail)
  u16*   KK   = (u16*)(w + 64 * MB);   // [64,192): full M x FF bf16 (after deps dead)
  u16*   wkT  = (u16*)(w + 192 * MB);  // 2 MB each
  u16*   wvT  = (u16*)(w + 194 * MB);
  u16*   wrT  = (u16*)(w + 196 * MB);
  u16*   woT  = (u16*)(w + 198 * MB);
  u16*   cwkT = (u16*)(w + 200 * MB);  // 8 MB [FF,D]
  u16*   cwvT = (u16*)(w + 208 * MB);  // 8 MB [D,FF]
  u16*   cwrT = (u16*)(w + 216 * MB);  // 2 MB -> total 218 MB
  // scan scratch inside [96,128) (xr dead after K/V/R; KK written after scan):
  float* aggA = (float*)(w + 96 * MB);
  float* aggB = (float*)(w + 97 * MB);
  float* aggP = (float*)(w + 98 * MB);
  float* incA = (float*)(w + 99 * MB);
  float* incB = (float*)(w + 100 * MB);
  float* incP = (float*)(w + 101 * MB);

  // ---- mega-prologue: 7 transposes + lnmix3 (all independent roots) ----
  prologue_kernel<<<13312 + M, 256, 0, stream>>>(
      wk, wv, wr, wo, cwk, cwv, cwr,
      wkT, wvT, wrT, woT, cwkT, cwvT, cwrT,
      x, ln1_g, ln1_b, tm_k, tm_v, tm_r, b32, b64, b96);

  // ---- fused K/V/R GEMMs (z selects; V now to its own region to avoid races) ----
  gemm_kvr<<<dim3(M / 256, D / 256, 3), 512, 0, stream>>>(
      b32, wkT, Kb, b64, wvT, Vb, b96, wrT, h);

  // chunk-parallel scan: a2 = bf16(r * wkv) -> b64 (xv dead)
  wkv_phase1<<<(NB * NCH * D) / 256, 256, 0, stream>>>(Kb, Vb, tdec, aggA, aggB, aggP);
  wkv_phase2<<<(NB * D) / 256, 256, 0, stream>>>(tdec, aggA, aggB, aggP, incA, incB, incP);
  wkv_phase3<<<(NB * NCH * D) / 256, 256, 0, stream>>>(Kb, Vb, h, tdec, tfir,
                                                       incA, incB, incP, b64);

  dim3 gD(M / 256, D / 256);      // (64, 4)
  // out = x + a2 @ wo
  gemm8<2><<<gD, 512, 0, stream>>>(b64, woT, D, D, out, nullptr, x, nullptr, nullptr);

  // ---- channel mixing (fused LN+mix) ----
  lnmix2_kernel<<<M, 256, 0, stream>>>(out, ln2_g, ln2_b, cm_k, cm_r, b32, b64); // xck, xcr

  // rr = sigmoid(xcr @ cwr) (bf16) -> h (R dead)
  gemm8<1><<<gD, 512, 0, stream>>>(b64, cwrT, D, D, nullptr, h, nullptr, nullptr, nullptr);

  // KK = relu(xck @ cwk)^2 (bf16) -> [64,192) (xcr/scratch/Kb/Vb all dead)
  dim3 gF(M / 256, FF / 256);     // (64, 16)
  gemm8<3><<<gF, 512, 0, stream>>>(b32, cwkT, FF, D, nullptr, KK, nullptr, nullptr, nullptr);

  // out += rr * (KK @ cwv)
  dim3 gO(M / 256, D / 256);      // (64, 4), K = FF
  gemm8<4><<<gO, 512, 0, stream>>>(KK, cwvT, D, FF, nullptr, nullptr, nullptr, h, out);
}